// Round 8
// baseline (1138.196 us; speedup 1.0000x reference)
//
#include <hip/hip_runtime.h>
#include <hip/hip_bf16.h>

#define B_   32
#define T_   2048
#define DIN  512
#define DM   1024
#define K_   64
#define BT   64
#define NC   (T_/BT)    // 32 chunks
#define MT   (DM/64)    // 16 m-tiles
#define LDSTR 68        // padded LDS row stride (floats)

typedef unsigned short u16;
typedef unsigned int   u32;

__device__ __forceinline__ float bf2f(u16 h) {
    return __uint_as_float(((u32)h) << 16);
}
__device__ __forceinline__ void bf2x2(u32 w, float& lo, float& hi) {
    lo = __uint_as_float(w << 16);
    hi = __uint_as_float(w & 0xffff0000u);
}
__device__ __forceinline__ u16 f2bf(float f) {   // round-to-nearest-even
    u32 u = __float_as_uint(f);
    u += 0x7fffu + ((u >> 16) & 1u);
    return (u16)(u >> 16);
}
__device__ __forceinline__ float softplusf(float z) {
    return fmaxf(z, 0.0f) + log1pf(expf(-fabsf(z)));
}

// async global->LDS, 16B per lane. Global src is PER-LANE (pass base+lane*16B);
// LDS dest is WAVE-UNIFORM base (HW adds lane*16). [guide §5, m97/m104]
__device__ __forceinline__ void gll16(const u32* g, unsigned char* l) {
    __builtin_amdgcn_global_load_lds(
        (const __attribute__((address_space(1))) u32*)g,
        (__attribute__((address_space(3))) u32*)l,
        16, 0, 0);
}

// ---- dtype-agnostic loaders -------------------------------------------------
template<bool BF16>
__device__ __forceinline__ float ld1(const void* p, size_t i) {
    if (BF16) return bf2f(((const u16*)p)[i]);
    else      return ((const float*)p)[i];
}
template<bool BF16>
__device__ __forceinline__ void ld2(const void* p, size_t i, float& a, float& b) {
    if (BF16) { u32 w = *(const u32*)((const u16*)p + i); bf2x2(w, a, b); }
    else      { float2 v = *(const float2*)((const float*)p + i); a = v.x; b = v.y; }
}
template<bool BF16>
__device__ __forceinline__ void ld8(const void* p, size_t i, float* a) {
    if (BF16) {
        uint4 v = *(const uint4*)((const u16*)p + i);
        bf2x2(v.x, a[0], a[1]); bf2x2(v.y, a[2], a[3]);
        bf2x2(v.z, a[4], a[5]); bf2x2(v.w, a[6], a[7]);
    } else {
        float4 v0 = *(const float4*)((const float*)p + i);
        float4 v1 = *(const float4*)((const float*)p + i + 4);
        a[0]=v0.x; a[1]=v0.y; a[2]=v0.z; a[3]=v0.w;
        a[4]=v1.x; a[5]=v1.y; a[6]=v1.z; a[7]=v1.w;
    }
}

// ---- device-side dtype sniff (block-uniform; needs blockDim.x >= 64) --------
__device__ __forceinline__ bool sniff_is_bf16(const void* xraw) {
    __shared__ int flag_s;
    if (threadIdx.x < 64) {
        u16 w = ((const u16*)xraw)[threadIdx.x];
        float av = fabsf(bf2f(w));
        bool plausible = (av == 0.0f) || (av >= 9.094947e-13f && av <= 64.0f);
        unsigned long long m = __ballot(plausible ? 1 : 0);
        if (threadIdx.x == 0) flag_s = (__popcll(m) >= 56) ? 1 : 0;
    }
    __syncthreads();
    return flag_s != 0;
}

// ---------------------------------------------------------------------------
// zero-init the fp32 accumulator region inside d_out.
// ---------------------------------------------------------------------------
__global__ __launch_bounds__(64) void zero_accum_kernel(const void* x, void* out) {
    bool isbf = sniff_is_bf16(x);
    float* outf = (float*)out;
    if (threadIdx.x < 32) {
        if (isbf) outf[threadIdx.x] = 0.0f;
        else      outf[64 + threadIdx.x] = 0.0f;
    }
}

// ===========================================================================
// Shared MFMA machinery (layouts HW-validated in R1/R2).
// ===========================================================================
typedef __attribute__((ext_vector_type(8)))  short bf16x8;   // 8 bf16 = 4 VGPR
typedef __attribute__((ext_vector_type(16))) float f32x16;   // 32x32 acc

#define TCH 128          // t rows per chunk
#define NCH (T_/TCH)     // 16 chunks
#define A_OFF  0
#define W_OFF  16384
#define AL_OFF 0         // alphaS: 128x64 f32 = 32KB (scan phase)
#define DR_OFF 32768     // driveS: 128x64 f32 = 32KB (scan phase)

// workspace layout (bytes):
//   [0, 64K)                 : parity column-sum accumulators (32 x 512 f32)
//   [64K, 64K+6M)            : W frags (full path) OR W planes (R2 mid path)
//   [64K+6M, 64K+6M+128M)    : X frags (full path only)
#define WS_COL_FLOATS  16384
#define WS_W_OFF_F     16384
#define WS_W_PLANE_U32 (3*256*1024)
#define WS_WFRAG_OFF_B 65536ULL
#define WS_WFRAG_BYTES (16ULL*16*24*1024)          // 6 MiB
#define WS_XFRAG_OFF_B (WS_WFRAG_OFF_B + WS_WFRAG_BYTES)
#define WS_XFRAG_BYTES (32ULL*16*16*16*1024)       // 128 MiB
#define WS_FULL_BYTES  (WS_XFRAG_OFF_B + WS_XFRAG_BYTES)

// ---------------------------------------------------------------------------
// bf16-path fused SSM on MFMA — UNCHANGED (hardware-validated, not timed).
// ---------------------------------------------------------------------------
#define KC  64
__global__ __launch_bounds__(256, 2) void fused_ssm_mfma_bf16(
    const void* __restrict__ x,
    const void* __restrict__ Wlam, const void* __restrict__ blam,
    const void* __restrict__ Wdelt, const void* __restrict__ bdelt,
    const void* __restrict__ Winp, const void* __restrict__ binp,
    const void* __restrict__ Wadd,
    void* __restrict__ out)
{
    __shared__ __align__(16) unsigned char LDS[65536];

    const int tid = threadIdx.x;

    {   // inline dtype sniff (flag in LDS[0]); bf16 only proceeds
        int* flag = (int*)LDS;
        if (tid < 64) {
            u16 w0 = ((const u16*)x)[tid];
            float av = fabsf(bf2f(w0));
            bool plausible = (av == 0.0f) || (av >= 9.094947e-13f && av <= 64.0f);
            unsigned long long m = __ballot(plausible ? 1 : 0);
            if (tid == 0) *flag = (__popcll(m) >= 56) ? 1 : 0;
        }
        __syncthreads();
        int isbf = *flag;
        __syncthreads();
        if (!isbf) return;
    }

    const int swz = (blockIdx.x & 7) * 64 + (blockIdx.x >> 3);
    const int mg  = swz & 15;
    const int b   = swz >> 4;
    const int m0  = mg * 64;

    const int lane = tid & 63;
    const int w    = tid >> 6;
    const int p    = w >> 1;
    const int h    = w & 1;
    const int lr   = lane & 31;
    const int lg   = lane >> 5;

    const int colg = m0 + h*32 + lr;
    const float bL = bf2f(((const u16*)blam )[colg]);
    const float bD = bf2f(((const u16*)bdelt)[colg]);
    const float bI = bf2f(((const u16*)binp )[colg]);

    float* alphaS = (float*)(LDS + AL_OFF);
    float* driveS = (float*)(LDS + DR_OFF);

    float scarry = 0.0f;

    #pragma unroll 1
    for (int c = 0; c < NCH; c++) {
        f32x16 aL0, aL1, aD0, aD1, aI0, aI1;
        #pragma unroll
        for (int r = 0; r < 16; r++) {
            aL0[r] = bL; aL1[r] = bL;
            aD0[r] = bD; aD1[r] = bD;
            aI0[r] = bI; aI1[r] = bI;
        }

        #pragma unroll 1
        for (int kc = 0; kc < DIN/KC; kc++) {
            {
                const int t_l  = tid >> 1;
                const int half = tid & 1;
                const u16* xp = (const u16*)x
                    + ((size_t)b*T_ + (size_t)c*TCH + t_l)*DIN + kc*KC + half*32;
                uint4 v[4];
                v[0] = *(const uint4*)(xp);
                v[1] = *(const uint4*)(xp + 8);
                v[2] = *(const uint4*)(xp + 16);
                v[3] = *(const uint4*)(xp + 24);
                const int tt = t_l >> 5, tr = t_l & 31;
                #pragma unroll
                for (int q = 0; q < 4; q++) {
                    const int o  = half*4 + q;
                    const int ks = o >> 1, g = o & 1;
                    *(uint4*)(LDS + A_OFF + ((tt*4 + ks) << 10) + ((g*32 + tr) << 4)) = v[q];
                }
            }
            #pragma unroll
            for (int i = 0; i < 6; i++) {
                const int f   = w + 4*i;
                const int nt  = f >> 2, ks = f & 3;
                const int hh  = (nt >= 3) ? 1 : 0;
                const int mat = nt - 3*hh;
                const u16* Wp = (const u16*)(mat == 0 ? Wlam : (mat == 1 ? Wdelt : Winp));
                const size_t base = (size_t)(kc*KC + ks*16 + lg*8)*DM + (size_t)(m0 + hh*32 + lr);
                u32 e0 = Wp[base        ];
                u32 e1 = Wp[base +   DM ];
                u32 e2 = Wp[base + 2*DM ];
                u32 e3 = Wp[base + 3*DM ];
                u32 e4 = Wp[base + 4*DM ];
                u32 e5 = Wp[base + 5*DM ];
                u32 e6 = Wp[base + 6*DM ];
                u32 e7 = Wp[base + 7*DM ];
                uint4 pk;
                pk.x = e0 | (e1 << 16);
                pk.y = e2 | (e3 << 16);
                pk.z = e4 | (e5 << 16);
                pk.w = e6 | (e7 << 16);
                *(uint4*)(LDS + W_OFF + (f << 10) + (lane << 4)) = pk;
            }
            __syncthreads();

            #pragma unroll
            for (int ks = 0; ks < 4; ks++) {
                bf16x8 a0 = *(const bf16x8*)(LDS + A_OFF + (((2*p    )*4 + ks) << 10) + (lane << 4));
                bf16x8 a1 = *(const bf16x8*)(LDS + A_OFF + (((2*p + 1)*4 + ks) << 10) + (lane << 4));
                bf16x8 vL = *(const bf16x8*)(LDS + W_OFF + (((h*3 + 0)*4 + ks) << 10) + (lane << 4));
                bf16x8 vD = *(const bf16x8*)(LDS + W_OFF + (((h*3 + 1)*4 + ks) << 10) + (lane << 4));
                bf16x8 vI = *(const bf16x8*)(LDS + W_OFF + (((h*3 + 2)*4 + ks) << 10) + (lane << 4));
                aL0 = __builtin_amdgcn_mfma_f32_32x32x16_bf16(a0, vL, aL0, 0, 0, 0);
                aL1 = __builtin_amdgcn_mfma_f32_32x32x16_bf16(a1, vL, aL1, 0, 0, 0);
                aD0 = __builtin_amdgcn_mfma_f32_32x32x16_bf16(a0, vD, aD0, 0, 0, 0);
                aD1 = __builtin_amdgcn_mfma_f32_32x32x16_bf16(a1, vD, aD1, 0, 0, 0);
                aI0 = __builtin_amdgcn_mfma_f32_32x32x16_bf16(a0, vI, aI0, 0, 0, 0);
                aI1 = __builtin_amdgcn_mfma_f32_32x32x16_bf16(a1, vI, aI1, 0, 0, 0);
            }
            __syncthreads();
        }

        #pragma unroll
        for (int tt2 = 0; tt2 < 2; tt2++) {
            #pragma unroll
            for (int r = 0; r < 16; r++) {
                const float zl = tt2 ? aL1[r] : aL0[r];
                const float zd = tt2 ? aD1[r] : aD0[r];
                const float zi = tt2 ? aI1[r] : aI0[r];
                const float lam = softplusf(zl);
                const float dl  = softplusf(zd);
                const float av  = expf(-dl * lam);
                const float dv  = dl * zi;
                const int t_loc = (2*p + tt2)*32 + (r & 3) + 8*(r >> 2) + 4*lg;
                const int m_loc = h*32 + lr;
                alphaS[t_loc*64 + m_loc] = av;
                driveS[t_loc*64 + m_loc] = dv;
            }
        }
        __syncthreads();

        if (tid < 64) {
            float s = scarry;
            #pragma unroll 8
            for (int t = 0; t < TCH; t++)
                s = fmaf(alphaS[t*64 + tid], s, driveS[t*64 + tid]);
            scarry = s;
        }
        __syncthreads();
    }

    if (tid < 64) {
        float partial = scarry * bf2f(((const u16*)Wadd)[m0 + tid]);
        #pragma unroll
        for (int off = 32; off > 0; off >>= 1)
            partial += __shfl_down(partial, off, 64);
        if (tid == 0)
            atomicAdd(&((float*)out)[b], partial);
    }
}

// ---------------------------------------------------------------------------
// R2 mid-path precursor — W planes, pair-packed (kept as fallback).
// ---------------------------------------------------------------------------
__global__ __launch_bounds__(256) void convert_w_kernel(
    const void* __restrict__ x,
    const void* __restrict__ Wlam, const void* __restrict__ Wdelt,
    const void* __restrict__ Winp, float* __restrict__ ws)
{
    if (sniff_is_bf16(x)) return;
    const int mat = blockIdx.x >> 8;
    const int kp  = blockIdx.x & 255;
    const float* Wp = (mat == 0) ? (const float*)Wlam
                    : (mat == 1) ? (const float*)Wdelt : (const float*)Winp;
    u32* whi = (u32*)(ws + WS_W_OFF_F);
    u32* wlo = whi + WS_W_PLANE_U32;
    const size_t ro = (size_t)(2*kp)*DM;
    const size_t wo = ((size_t)mat*256 + kp)*DM;
    #pragma unroll
    for (int mm = 0; mm < 4; mm++) {
        const int m = mm*256 + threadIdx.x;
        float a0 = Wp[ro + m];
        float a1 = Wp[ro + DM + m];
        u16 h0 = f2bf(a0), h1 = f2bf(a1);
        float l0 = a0 - bf2f(h0);
        float l1 = a1 - bf2f(h1);
        whi[wo + m] = (u32)h0 | ((u32)h1 << 16);
        wlo[wo + m] = (__float_as_uint(l0) >> 16) | (__float_as_uint(l1) & 0xffff0000u);
    }
}

// ---------------------------------------------------------------------------
// W -> frag-linear split-bf16: wsw[mg][kc][f(24)][1KB].
// ---------------------------------------------------------------------------
__global__ __launch_bounds__(256) void convert_w_frag_kernel(
    const void* __restrict__ x,
    const void* __restrict__ Wlam, const void* __restrict__ Wdelt,
    const void* __restrict__ Winp, u32* __restrict__ wsw)
{
    if (sniff_is_bf16(x)) return;
    const int kc = blockIdx.x & 15;
    const int mg = blockIdx.x >> 4;
    const int m0 = mg*64;
    u32* dst = wsw + (size_t)(mg*16 + kc) * 6144;   // 24*256 u32
    #pragma unroll
    for (int i = 0; i < 6; i++) {
        const int u = threadIdx.x + 256*i;   // 0..1535
        const int f = u >> 6;                // 0..23
        const int l = u & 63;
        const int hl = f & 1, ks = (f >> 1) & 1, nt = f >> 2;
        const int hh = nt / 3, mat = nt % 3;
        const float* Wp = (mat == 0) ? (const float*)Wlam
                        : (mat == 1) ? (const float*)Wdelt : (const float*)Winp;
        const int lr = l & 31, lg = l >> 5;
        const int kp0 = kc*16 + ks*8 + lg*4;
        const int m = m0 + hh*32 + lr;
        u32 q4[4];
        #pragma unroll
        for (int q = 0; q < 4; q++) {
            float a0 = Wp[(size_t)(2*(kp0+q)    )*DM + m];
            float a1 = Wp[(size_t)(2*(kp0+q) + 1)*DM + m];
            u16 h0 = f2bf(a0), h1 = f2bf(a1);
            if (hl == 0) {
                q4[q] = (u32)h0 | ((u32)h1 << 16);
            } else {
                float l0 = a0 - bf2f(h0);
                float l1 = a1 - bf2f(h1);
                q4[q] = (__float_as_uint(l0) >> 16) | (__float_as_uint(l1) & 0xffff0000u);
            }
        }
        *(uint4*)(dst + f*256 + l*4) = make_uint4(q4[0], q4[1], q4[2], q4[3]);
    }
}

// ---------------------------------------------------------------------------
// x -> frag-linear split-bf16: wsx[b][c][kc][f(16)][1KB].
// Identical arithmetic to the R2 in-kernel conversion (bit-identical result).
// ---------------------------------------------------------------------------
#define KC2 32
__global__ __launch_bounds__(256) void convert_x_kernel(
    const void* __restrict__ x, u32* __restrict__ wsx)
{
    if (sniff_is_bf16(x)) return;
    const int kc = blockIdx.x & 15;
    const int c  = (blockIdx.x >> 4) & 15;
    const int b  = blockIdx.x >> 8;
    const int tid = threadIdx.x;
    const int t_l  = tid >> 1;          // 0..127
    const int half = tid & 1;           // = ks
    const float* xp = (const float*)x
        + ((size_t)b*T_ + (size_t)c*TCH + t_l)*DIN + kc*KC2 + half*16;
    float vv[16];
    *(float4*)(vv)      = *(const float4*)(xp);
    *(float4*)(vv + 4)  = *(const float4*)(xp + 4);
    *(float4*)(vv + 8)  = *(const float4*)(xp + 8);
    *(float4*)(vv + 12) = *(const float4*)(xp + 12);
    u32 hi[8], lo[8];
    #pragma unroll
    for (int q = 0; q < 8; q++) {
        const float a0 = vv[2*q], a1 = vv[2*q+1];
        const u16 h0 = f2bf(a0), h1 = f2bf(a1);
        hi[q] = (u32)h0 | ((u32)h1 << 16);
        const float l0 = a0 - bf2f(h0);
        const float l1 = a1 - bf2f(h1);
        lo[q] = (__float_as_uint(l0) >> 16) | (__float_as_uint(l1) & 0xffff0000u);
    }
    u32* dst = wsx + ((((size_t)b*16 + c)*16 + kc) << 12);   // *4096 u32
    const int tt = t_l >> 5, tr = t_l & 31;
    const int fb = (tt*2 + half)*2;
    *(uint4*)(dst + fb*256     + (0*32 + tr)*4) = make_uint4(hi[0],hi[1],hi[2],hi[3]);
    *(uint4*)(dst + fb*256     + (1*32 + tr)*4) = make_uint4(hi[4],hi[5],hi[6],hi[7]);
    *(uint4*)(dst + (fb+1)*256 + (0*32 + tr)*4) = make_uint4(lo[0],lo[1],lo[2],lo[3]);
    *(uint4*)(dst + (fb+1)*256 + (1*32 + tr)*4) = make_uint4(lo[4],lo[5],lo[6],lo[7]);
}

// ---------------------------------------------------------------------------
// fp32-path fused SSM, full-workspace variant (R8: R7's double-buffer with
// global_load_lds staging — no ds_writes, no staging VGPRs, no VGPR
// round-trip. Per kc: [issue 10 gll16 into nxt] -> [20 ds_read + 36 MFMA on
// cur] -> [__syncthreads drains vmcnt, loads had the MFMA phase to land].
// MFMA/activation/scan identical to R7 (bit-identical numerics).
// ---------------------------------------------------------------------------
#define STG_B 40960   // one staging buffer: A 16KB @ +0, W 24KB @ +16384
__global__ __launch_bounds__(256, 2) void fused_ssm_mfma_fp32_full(
    const void* __restrict__ x,
    const void* __restrict__ blam, const void* __restrict__ bdelt,
    const void* __restrict__ binp, const void* __restrict__ Wadd,
    const u32* __restrict__ wsw, const u32* __restrict__ wsx,
    void* __restrict__ out)
{
    __shared__ __align__(16) unsigned char LDS[2*STG_B];   // 80 KB

    const int tid = threadIdx.x;

    {   // inline dtype sniff; fp32 only proceeds
        int* flag = (int*)LDS;
        if (tid < 64) {
            u16 w0 = ((const u16*)x)[tid];
            float av = fabsf(bf2f(w0));
            bool plausible = (av == 0.0f) || (av >= 9.094947e-13f && av <= 64.0f);
            unsigned long long m = __ballot(plausible ? 1 : 0);
            if (tid == 0) *flag = (__popcll(m) >= 56) ? 1 : 0;
        }
        __syncthreads();
        int isbf = *flag;
        __syncthreads();
        if (isbf) return;
    }

    const int swz = (blockIdx.x & 7) * 64 + (blockIdx.x >> 3);
    const int mg  = swz & 15;
    const int b   = swz >> 4;
    const int m0  = mg * 64;

    const int lane = tid & 63;
    const int w    = tid >> 6;
    const int p    = w >> 1;
    const int h    = w & 1;
    const int lr   = lane & 31;
    const int lg   = lane >> 5;

    const int colg = m0 + h*32 + lr;
    const float bL = ((const float*)blam )[colg];
    const float bD = ((const float*)bdelt)[colg];
    const float bI = ((const float*)binp )[colg];

    float* alphaS = (float*)(LDS + AL_OFF);
    float* driveS = (float*)(LDS + DR_OFF);

    // wave-local staging sources (per-lane global addresses; u32 units)
    const u32* gwB = wsw + (size_t)(mg*16)*6144 + (size_t)(w*6)*256 + (size_t)lane*4;

    float scarry = 0.0f;

    #pragma unroll 1
    for (int c = 0; c < NCH; c++) {
        f32x16 aL0, aL1, aD0, aD1, aI0, aI1;
        #pragma unroll
        for (int r = 0; r < 16; r++) {
            aL0[r] = bL; aL1[r] = bL;
            aD0[r] = bD; aD1[r] = bD;
            aI0[r] = bI; aI1[r] = bI;
        }

        const u32* gaB = wsx + ((((size_t)b*16 + c)*16) << 12)
                             + (size_t)(w*4)*256 + (size_t)lane*4;

        // ---- chunk prologue: stage kc=0 into buf0 via global_load_lds ----
        {
            unsigned char* la = LDS + (w*4)*1024;
            gll16(gaB,        la);
            gll16(gaB + 256,  la + 1024);
            gll16(gaB + 512,  la + 2048);
            gll16(gaB + 768,  la + 3072);
            unsigned char* lw = LDS + 16384 + (w*6)*1024;
            gll16(gwB,         lw);
            gll16(gwB + 256,   lw + 1024);
            gll16(gwB + 512,   lw + 2048);
            gll16(gwB + 768,   lw + 3072);
            gll16(gwB + 1024,  lw + 4096);
            gll16(gwB + 1280,  lw + 5120);
        }
        __syncthreads();   // drains vmcnt -> buf0 resident

        #pragma unroll 1
        for (int kc = 0; kc < DIN/KC2; kc++) {
            unsigned char* cur = LDS + (kc & 1)*STG_B;
            unsigned char* nxt = LDS + ((kc + 1) & 1)*STG_B;

            // ---- 1. issue next-kc gll16 into nxt (drain under MFMAs) ----
            if (kc < DIN/KC2 - 1) {
                const u32* ga = gaB + (size_t)(kc + 1)*4096;
                const u32* gw = gwB + (size_t)(kc + 1)*6144;
                unsigned char* la = nxt + (w*4)*1024;
                gll16(ga,        la);
                gll16(ga + 256,  la + 1024);
                gll16(ga + 512,  la + 2048);
                gll16(ga + 768,  la + 3072);
                unsigned char* lw = nxt + 16384 + (w*6)*1024;
                gll16(gw,         lw);
                gll16(gw + 256,   lw + 1024);
                gll16(gw + 512,   lw + 2048);
                gll16(gw + 768,   lw + 3072);
                gll16(gw + 1024,  lw + 4096);
                gll16(gw + 1280,  lw + 5120);
            }

            // ---- 2. MFMA on current buffer: 2 K-steps x (2 tt x 3 mats x 3)
            #pragma unroll
            for (int ks = 0; ks < 2; ks++) {
                const int fa0 = ((2*p    )*2 + ks)*2;
                const int fa1 = ((2*p + 1)*2 + ks)*2;
                const int fL  = ((h*3 + 0)*2 + ks)*2;
                const int fD  = ((h*3 + 1)*2 + ks)*2;
                const int fI  = ((h*3 + 2)*2 + ks)*2;
                bf16x8 a0h = *(const bf16x8*)(cur + (fa0     << 10) + (lane << 4));
                bf16x8 a0l = *(const bf16x8*)(cur + ((fa0+1) << 10) + (lane << 4));
                bf16x8 a1h = *(const bf16x8*)(cur + (fa1     << 10) + (lane << 4));
                bf16x8 a1l = *(const bf16x8*)(cur + ((fa1+1) << 10) + (lane << 4));
                bf16x8 vLh = *(const bf16x8*)(cur + 16384 + (fL      << 10) + (lane << 4));
                bf16x8 vLl = *(const bf16x8*)(cur + 16384 + ((fL+1)  << 10) + (lane << 4));
                bf16x8 vDh = *(const bf16x8*)(cur + 16384 + (fD      << 10) + (lane << 4));
                bf16x8 vDl = *(const bf16x8*)(cur + 16384 + ((fD+1)  << 10) + (lane << 4));
                bf16x8 vIh = *(const bf16x8*)(cur + 16384 + (fI      << 10) + (lane << 4));
                bf16x8 vIl = *(const bf16x8*)(cur + 16384 + ((fI+1)  << 10) + (lane << 4));
                aL0 = __builtin_amdgcn_mfma_f32_32x32x16_bf16(a0h, vLh, aL0, 0, 0, 0);
                aL0 = __builtin_amdgcn_mfma_f32_32x32x16_bf16(a0h, vLl, aL0, 0, 0, 0);
                aL0 = __builtin_amdgcn_mfma_f32_32x32x16_bf16(a0l, vLh, aL0, 0, 0, 0);
                aL1 = __builtin_amdgcn_mfma_f32_32x32x16_bf16(a1h, vLh, aL1, 0, 0, 0);
                aL1 = __builtin_amdgcn_mfma_f32_32x32x16_bf16(a1h, vLl, aL1, 0, 0, 0);
                aL1 = __builtin_amdgcn_mfma_f32_32x32x16_bf16(a1l, vLh, aL1, 0, 0, 0);
                aD0 = __builtin_amdgcn_mfma_f32_32x32x16_bf16(a0h, vDh, aD0, 0, 0, 0);
                aD0 = __builtin_amdgcn_mfma_f32_32x32x16_bf16(a0h, vDl, aD0, 0, 0, 0);
                aD0 = __builtin_amdgcn_mfma_f32_32x32x16_bf16(a0l, vDh, aD0, 0, 0, 0);
                aD1 = __builtin_amdgcn_mfma_f32_32x32x16_bf16(a1h, vDh, aD1, 0, 0, 0);
                aD1 = __builtin_amdgcn_mfma_f32_32x32x16_bf16(a1h, vDl, aD1, 0, 0, 0);
                aD1 = __builtin_amdgcn_mfma_f32_32x32x16_bf16(a1l, vDh, aD1, 0, 0, 0);
                aI0 = __builtin_amdgcn_mfma_f32_32x32x16_bf16(a0h, vIh, aI0, 0, 0, 0);
                aI0 = __builtin_amdgcn_mfma_f32_32x32x16_bf16(a0h, vIl, aI0, 0, 0, 0);
                aI0 = __builtin_amdgcn_mfma_f32_32x32x16_bf16(a0l, vIh, aI0, 0, 0, 0);
                aI1 = __builtin_amdgcn_mfma_f32_32x32x16_bf16(a1h, vIh, aI1, 0, 0, 0);
                aI1 = __builtin_amdgcn_mfma_f32_32x32x16_bf16(a1h, vIl, aI1, 0, 0, 0);
                aI1 = __builtin_amdgcn_mfma_f32_32x32x16_bf16(a1l, vIh, aI1, 0, 0, 0);
            }

            __syncthreads();   // drains vmcnt (nxt resident) + cur fully read
        }

        // ---- activation (lane-local) -> alpha/drive in LDS ----
        #pragma unroll
        for (int tt2 = 0; tt2 < 2; tt2++) {
            #pragma unroll
            for (int r = 0; r < 16; r++) {
                const float zl = tt2 ? aL1[r] : aL0[r];
                const float zd = tt2 ? aD1[r] : aD0[r];
                const float zi = tt2 ? aI1[r] : aI0[r];
                const float lam = softplusf(zl);
                const float dl  = softplusf(zd);
                const float av  = expf(-dl * lam);
                const float dv  = dl * zi;
                const int t_loc = (2*p + tt2)*32 + (r & 3) + 8*(r >> 2) + 4*lg;
                const int m_loc = h*32 + lr;
                alphaS[t_loc*64 + m_loc] = av;
                driveS[t_loc*64 + m_loc] = dv;
            }
        }
        __syncthreads();

        // ---- in-chunk scan, one thread per m column ----
        if (tid < 64) {
            float s = scarry;
            #pragma unroll 8
            for (int t = 0; t < TCH; t++)
                s = fmaf(alphaS[t*64 + tid], s, driveS[t*64 + tid]);
            scarry = s;
        }
        __syncthreads();
    }

    if (tid < 64) {
        float partial = scarry * ((const float*)Wadd)[m0 + tid];
        #pragma unroll
        for (int off = 32; off > 0; off >>= 1)
            partial += __shfl_down(partial, off, 64);
        if (tid == 0)
            atomicAdd(&((float*)out)[64 + b], partial);
    }
}

// ---------------------------------------------------------------------------
// R2 fp32-path fused SSM (mid-workspace fallback) — unchanged.
// ---------------------------------------------------------------------------
__global__ __launch_bounds__(256, 2) void fused_ssm_mfma_fp32_ws6(
    const void* __restrict__ x,
    const void* __restrict__ blam, const void* __restrict__ bdelt,
    const void* __restrict__ binp, const void* __restrict__ Wadd,
    const float* __restrict__ ws,
    void* __restrict__ out)
{
    __shared__ __align__(16) unsigned char LDS[65536];

    const int tid = threadIdx.x;

    {
        int* flag = (int*)LDS;
        if (tid < 64) {
            u16 w0 = ((const u16*)x)[tid];
            float av = fabsf(bf2f(w0));
            bool plausible = (av == 0.0f) || (av >= 9.094947e-13f && av <= 64.0f);
            unsigned long long m = __ballot(plausible ? 1 : 0);
            if (tid == 0) *flag = (__popcll(m) >= 56) ? 1 : 0;
        }
        __syncthreads();
        int isbf = *flag;
        __syncthreads();
        if (isbf) return;
    }

    const u32* whi = (const u32*)(ws + WS_W_OFF_F);
    const u32* wlo = whi + WS_W_PLANE_U32;

    const int swz = (blockIdx.x & 7) * 64 + (blockIdx.x >> 3);
    const int mg  = swz & 15;
    const int b   = swz >> 4;
    const int m0  = mg * 64;

    const int lane = tid & 63;
    const int w    = tid >> 6;
    const int p    = w >> 1;
    const int h    = w & 1;
    const int lr   = lane & 31;
    const int lg   = lane >> 5;

    const int colg = m0 + h*32 + lr;
    const float bL = ((const float*)blam )[colg];
    const float bD = ((const float*)bdelt)[colg];
    const float bI = ((const float*)binp )[colg];

    int fhi_[3], kp0_[3]; size_t wb_[3];
    #pragma unroll
    for (int i = 0; i < 3; i++) {
        const int u2 = w + 4*i;
        const int ks = u2 & 1, mu = u2 >> 1;
        const int mat = mu % 3, hh = mu / 3;
        fhi_[i] = 2*u2;
        kp0_[i] = ks*8 + lg*4;
        wb_[i]  = ((size_t)mat*256)*DM + (size_t)(m0 + hh*32 + lr);
    }

    float* alphaS = (float*)(LDS + AL_OFF);
    float* driveS = (float*)(LDS + DR_OFF);

    float scarry = 0.0f;

    #pragma unroll 1
    for (int c = 0; c < NCH; c++) {
        f32x16 aL0, aL1, aD0, aD1, aI0, aI1;
        #pragma unroll
        for (int r = 0; r < 16; r++) {
            aL0[r] = bL; aL1[r] = bL;
            aD0[r] = bD; aD1[r] = bD;
            aI0[r] = bI; aI1[r] = bI;
        }

        #pragma unroll 1
        for (int kc = 0; kc < DIN/KC2; kc++) {
            {
                const int t_l  = tid >> 1;
                const int half = tid & 1;
                const float* xp = (const float*)x
                    + ((size_t)b*T_ + (size_t)c*TCH + t_l)*DIN + kc*KC2 + half*16;
                float vv[16];
                *(float4*)(vv)      = *(const float4*)(xp);
                *(float4*)(vv + 4)  = *(const float4*)(xp + 4);
                *(float4*)(vv + 8)  = *(const float4*)(xp + 8);
                *(float4*)(vv + 12) = *(const float4*)(xp + 12);
                u32 hi[8], lo[8];
                #pragma unroll
                for (int q = 0; q < 8; q++) {
                    const float a0 = vv[2*q], a1 = vv[2*q+1];
                    const u16 h0 = f2bf(a0), h1 = f2bf(a1);
                    hi[q] = (u32)h0 | ((u32)h1 << 16);
                    const float l0 = a0 - bf2f(h0);
                    const float l1 = a1 - bf2f(h1);
                    lo[q] = (__float_as_uint(l0) >> 16) | (__float_as_uint(l1) & 0xffff0000u);
                }
                const int tt = t_l >> 5, tr = t_l & 31;
                const int fb = (tt*2 + half)*2;
                *(uint4*)(LDS + A_OFF + (fb << 10)     + ((0*32 + tr) << 4)) = make_uint4(hi[0],hi[1],hi[2],hi[3]);
                *(uint4*)(LDS + A_OFF + (fb << 10)     + ((1*32 + tr) << 4)) = make_uint4(hi[4],hi[5],hi[6],hi[7]);
                *(uint4*)(LDS + A_OFF + ((fb+1) << 10) + ((0*32 + tr) << 4)) = make_uint4(lo[0],lo[1],lo[2],lo[3]);
                *(uint4*)(LDS + A_OFF + ((fb+1) << 10) + ((1*32 + tr) << 4)) = make_uint4(lo[4],lo[5],lo[6],lo[7]);
            }
            #pragma unroll
            for (int i = 0; i < 3; i++) {
                const size_t base = wb_[i] + (size_t)(kc*16 + kp0_[i])*DM;
                uint4 ph, pl;
                ph.x = whi[base]; ph.y = whi[base + DM]; ph.z = whi[base + 2*DM]; ph.w = whi[base + 3*DM];
                pl.x = wlo[base]; pl.y = wlo[base + DM]; pl.z = wlo[base + 2*DM]; pl.w = wlo[base + 3*DM];
                *(uint4*)(LDS + W_OFF + (fhi_[i] << 10)       + (lane << 4)) = ph;
                *(uint4*)(LDS + W_OFF + ((fhi_[i] + 1) << 10) + (lane << 4)) = pl;
            }
            __syncthreads();

            #pragma unroll
            for (int ks = 0; ks < 2; ks++) {
                const int fa0 = ((2*p    )*2 + ks)*2;
                const int fa1 = ((2*p + 1)*2 + ks)*2;
                const int fL  = ((h*3 + 0)*2 + ks)*2;
                const int fD  = ((h*3 + 1)*2 + ks)*2;
                const int fI  = ((h*3 + 2)*2 + ks)*2;
                bf16x8 a0h = *(const bf16x8*)(LDS + A_OFF + (fa0     << 10) + (lane << 4));
                bf16x8 a0l = *(const bf16x8*)(LDS + A_OFF + ((fa0+1) << 10) + (lane << 4));
                bf16x8 a1h = *(const bf16x8*)(LDS + A_OFF + (fa1     << 10) + (lane << 4));
                bf16x8 a1l = *(const bf16x8*)(LDS + A_OFF + ((fa1+1) << 10) + (lane << 4));
                bf16x8 vLh = *(const bf16x8*)(LDS + W_OFF + (fL      << 10) + (lane << 4));
                bf16x8 vLl = *(const bf16x8*)(LDS + W_OFF + ((fL+1)  << 10) + (lane << 4));
                bf16x8 vDh = *(const bf16x8*)(LDS + W_OFF + (fD      << 10) + (lane << 4));
                bf16x8 vDl = *(const bf16x8*)(LDS + W_OFF + ((fD+1)  << 10) + (lane << 4));
                bf16x8 vIh = *(const bf16x8*)(LDS + W_OFF + (fI      << 10) + (lane << 4));
                bf16x8 vIl = *(const bf16x8*)(LDS + W_OFF + ((fI+1)  << 10) + (lane << 4));
                aL0 = __builtin_amdgcn_mfma_f32_32x32x16_bf16(a0h, vLh, aL0, 0, 0, 0);
                aL0 = __builtin_amdgcn_mfma_f32_32x32x16_bf16(a0h, vLl, aL0, 0, 0, 0);
                aL0 = __builtin_amdgcn_mfma_f32_32x32x16_bf16(a0l, vLh, aL0, 0, 0, 0);
                aL1 = __builtin_amdgcn_mfma_f32_32x32x16_bf16(a1h, vLh, aL1, 0, 0, 0);
                aL1 = __builtin_amdgcn_mfma_f32_32x32x16_bf16(a1h, vLl, aL1, 0, 0, 0);
                aL1 = __builtin_amdgcn_mfma_f32_32x32x16_bf16(a1l, vLh, aL1, 0, 0, 0);
                aD0 = __builtin_amdgcn_mfma_f32_32x32x16_bf16(a0h, vDh, aD0, 0, 0, 0);
                aD0 = __builtin_amdgcn_mfma_f32_32x32x16_bf16(a0h, vDl, aD0, 0, 0, 0);
                aD0 = __builtin_amdgcn_mfma_f32_32x32x16_bf16(a0l, vDh, aD0, 0, 0, 0);
                aD1 = __builtin_amdgcn_mfma_f32_32x32x16_bf16(a1h, vDh, aD1, 0, 0, 0);
                aD1 = __builtin_amdgcn_mfma_f32_32x32x16_bf16(a1h, vDl, aD1, 0, 0, 0);
                aD1 = __builtin_amdgcn_mfma_f32_32x32x16_bf16(a1l, vDh, aD1, 0, 0, 0);
                aI0 = __builtin_amdgcn_mfma_f32_32x32x16_bf16(a0h, vIh, aI0, 0, 0, 0);
                aI0 = __builtin_amdgcn_mfma_f32_32x32x16_bf16(a0h, vIl, aI0, 0, 0, 0);
                aI0 = __builtin_amdgcn_mfma_f32_32x32x16_bf16(a0l, vIh, aI0, 0, 0, 0);
                aI1 = __builtin_amdgcn_mfma_f32_32x32x16_bf16(a1h, vIh, aI1, 0, 0, 0);
                aI1 = __builtin_amdgcn_mfma_f32_32x32x16_bf16(a1h, vIl, aI1, 0, 0, 0);
                aI1 = __builtin_amdgcn_mfma_f32_32x32x16_bf16(a1l, vIh, aI1, 0, 0, 0);
            }
            __syncthreads();
        }

        #pragma unroll
        for (int tt2 = 0; tt2 < 2; tt2++) {
            #pragma unroll
            for (int r = 0; r < 16; r++) {
                const float zl = tt2 ? aL1[r] : aL0[r];
                const float zd = tt2 ? aD1[r] : aD0[r];
                const float zi = tt2 ? aI1[r] : aI0[r];
                const float lam = softplusf(zl);
                const float dl  = softplusf(zd);
                const float av  = expf(-dl * lam);
                const float dv  = dl * zi;
                const int t_loc = (2*p + tt2)*32 + (r & 3) + 8*(r >> 2) + 4*lg;
                const int m_loc = h*32 + lr;
                alphaS[t_loc*64 + m_loc] = av;
                driveS[t_loc*64 + m_loc] = dv;
            }
        }
        __syncthreads();

        if (tid < 64) {
            float s = scarry;
            #pragma unroll 8
            for (int t = 0; t < TCH; t++)
                s = fmaf(alphaS[t*64 + tid], s, driveS[t*64 + tid]);
            scarry = s;
        }
        __syncthreads();
    }

    if (tid < 64) {
        float partial = scarry * ((const float*)Wadd)[m0 + tid];
        #pragma unroll
        for (int off = 32; off > 0; off >>= 1)
            partial += __shfl_down(partial, off, 64);
        if (tid == 0)
            atomicAdd(&((float*)out)[64 + b], partial);
    }
}

// ---------------------------------------------------------------------------
// fp32-path fused SSM on VALU — last-resort fallback (no workspace).
// ---------------------------------------------------------------------------
template<bool BF16>
__global__ __launch_bounds__(256) void fused_ssm_kernel(
    const void* __restrict__ x,
    const void* __restrict__ Wlam, const void* __restrict__ blam,
    const void* __restrict__ Wdelt, const void* __restrict__ bdelt,
    const void* __restrict__ Winp, const void* __restrict__ binp,
    const void* __restrict__ Wadd,
    void* __restrict__ out)
{
    if (sniff_is_bf16(x) != BF16) return;

    __shared__ __align__(16) float smem[8704];

    const int mt  = blockIdx.x & 15;
    const int b   = blockIdx.x >> 4;
    const int tid = threadIdx.x;
    const int tx  = tid & 15;
    const int ty  = tid >> 4;

    float bl[4], bd[4], bi[4];
    #pragma unroll
    for (int jj = 0; jj < 4; jj++) {
        int m = mt*64 + tx*4 + jj;
        bl[jj] = ld1<BF16>(blam, m); bd[jj] = ld1<BF16>(bdelt, m); bi[jj] = ld1<BF16>(binp, m);
    }

    float* xsT = smem;
    float* w3  = smem + 32*LDSTR;
    float* alphaS = smem;
    float* driveS = smem + 64*LDSTR;

    const int t_s = tid >> 2;
    const int ko  = (tid & 3) * 8;
    const int wk  = tid >> 3;
    const int wmo = (tid & 7) * 8;

    float scarry = 0.0f;

    for (int c = 0; c < NC; c++) {
        float acc0[4][4], acc1[4][4], acc2[4][4];
        #pragma unroll
        for (int ii = 0; ii < 4; ii++)
            #pragma unroll
            for (int jj = 0; jj < 4; jj++) {
                acc0[ii][jj] = bl[jj]; acc1[ii][jj] = bd[jj]; acc2[ii][jj] = bi[jj];
            }

        const size_t xbase = ((size_t)b*T_ + (size_t)c*BT) * DIN;

        for (int kk0 = 0; kk0 < DIN; kk0 += 32) {
            {
                float a[8];
                ld8<BF16>(x, xbase + (size_t)t_s*DIN + kk0 + ko, a);
                #pragma unroll
                for (int q = 0; q < 8; q++)
                    xsT[(ko + q)*LDSTR + t_s] = a[q];
            }
            #pragma unroll
            for (int mat = 0; mat < 3; mat++) {
                const void* Wp = (mat == 0) ? Wlam : (mat == 1) ? Wdelt : Winp;
                float a[8];
                ld8<BF16>(Wp, (size_t)(kk0 + wk)*DM + mt*64 + wmo, a);
                float* dst = &w3[(mat*32 + wk)*LDSTR + wmo];
                *(float4*)(dst)     = make_float4(a[0],a[1],a[2],a[3]);
                *(float4*)(dst + 4) = make_float4(a[4],a[5],a[6],a[7]);
            }
            __syncthreads();

            #pragma unroll 8
            for (int kkk = 0; kkk < 32; kkk++) {
                float4 xa = *(const float4*)&xsT[kkk*LDSTR + ty*4];
                float4 w0 = *(const float4*)&w3[( 0 + kkk)*LDSTR + tx*4];
                float4 w1 = *(const float4*)&w3[(32 + kkk)*LDSTR + tx*4];
                float4 w2 = *(const float4*)&w3[(64 + kkk)*LDSTR + tx*4];
                float xv[4]  = {xa.x, xa.y, xa.z, xa.w};
                float w0v[4] = {w0.x, w0.y, w0.z, w0.w};
                float w1v[4] = {w1.x, w1.y, w1.z, w1.w};
                float w2v[4] = {w2.x, w2.y, w2.z, w2.w};
                #pragma unroll
                for (int ii = 0; ii < 4; ii++)
                    #pragma unroll
                    for (int jj = 0; jj < 4; jj++) {
                        acc0[ii][jj] = fmaf(xv[ii], w0v[jj], acc0[ii][jj]);
                        acc1[ii][jj] = fmaf(xv[ii], w1v[jj], acc1[ii][jj]);
                        acc2[ii][jj] = fmaf(xv[ii], w2v[jj], acc2[ii][jj]);
                    }
            }
            __syncthreads();
        }

        #pragma unroll
        for (int ii = 0; ii < 4; ii++) {
            int t = ty*4 + ii;
            float a[4], d[4];
            #pragma unroll
            for (int jj = 0; jj < 4; jj++) {
                float lam = softplusf(acc0[ii][jj]);
                float dl  = softplusf(acc1[ii][jj]);
                a[jj] = expf(-dl * lam);
                d[jj] = dl * acc2[ii][jj];
            }
            *(float4*)&alphaS[t*LDSTR + tx*4] = make_float4(a[0],a[1],a[2],a[3]);
            *(float4*)&driveS[t*LDSTR + tx*4] = make_float4(d[0],d[1],d[2],d[3]);
        }
        __syncthreads();

        if (tid < 64) {
            float s = scarry;
            #pragma unroll 8
            for (int t = 0; t < BT; t++)
                s = fmaf(alphaS[t*LDSTR + tid], s, driveS[t*LDSTR + tid]);
            scarry = s;
        }
        __syncthreads();
    }

    if (tid < 64) {
        float partial = scarry * ld1<BF16>(Wadd, mt*64 + tid);
        #pragma unroll
        for (int off = 32; off > 0; off >>= 1)
            partial += __shfl_down(partial, off, 64);
        if (tid == 0) {
            float* outf = (float*)out;
            atomicAdd(BF16 ? &outf[b] : &outf[64 + b], partial);
        }
    }
}

// ---------------------------------------------------------------------------
// add_pred finalize: fold accumulator + bias, write in output dtype.
// ---------------------------------------------------------------------------
template<bool BF16>
__global__ __launch_bounds__(64) void add_finalize_kernel(
    const void* x, const void* badd, void* out)
{
    if (sniff_is_bf16(x) != BF16) return;
    float bb = ld1<BF16>(badd, 0);
    if (threadIdx.x < 32) {
        float* outf = (float*)out;
        if (BF16) {
            float s = outf[threadIdx.x] + bb;
            ((u16*)out)[64 + threadIdx.x] = f2bf(s);
        } else {
            outf[64 + threadIdx.x] += bb;
        }
    }
}

// ---------------------------------------------------------------------------
// parity pipeline (workspace path): parallel column sums, then finish.
// ---------------------------------------------------------------------------
__global__ __launch_bounds__(256) void colsum_zero_kernel(float* ws) {
    ws[blockIdx.x*256 + threadIdx.x] = 0.0f;   // grid 64 -> 16384 floats
}

template<bool BF16>
__global__ __launch_bounds__(256) void parity_colsum_kernel(
    const void* __restrict__ x, float* __restrict__ ws)
{
    if (sniff_is_bf16(x) != BF16) return;
    const int b  = blockIdx.x >> 3;
    const int sl = blockIdx.x & 7;
    const int tid = threadIdx.x;
    float s0 = 0.0f, s1 = 0.0f;
    const size_t xb = (size_t)b * T_ * DIN;
    for (int t = sl*256; t < (sl+1)*256; t++) {
        float a, c2;
        ld2<BF16>(x, xb + (size_t)t*DIN + 2*tid, a, c2);
        s0 += a; s1 += c2;
    }
    atomicAdd(&ws[b*512 + 2*tid    ], s0);
    atomicAdd(&ws[b*512 + 2*tid + 1], s1);
}

template<bool BF16>
__global__ __launch_bounds__(256) void parity_finish_kernel(
    const void* __restrict__ x, const float* __restrict__ ws,
    const void* __restrict__ Wth, const void* __restrict__ bth,
    const void* __restrict__ Wpar, const void* __restrict__ bpar,
    void* __restrict__ out)
{
    if (sniff_is_bf16(x) != BF16) return;

    __shared__ float xsL[512];
    __shared__ float red[256];
    __shared__ float cosL[64], sinL[64];
    const int b = blockIdx.x;
    const int tid = threadIdx.x;

    xsL[tid]       = ws[b*512 + tid];
    xsL[256 + tid] = ws[b*512 + 256 + tid];
    __syncthreads();

    {
        const int k = tid & 63, seg = tid >> 6;
        float s = 0.0f;
        #pragma unroll 8
        for (int dd = 0; dd < 128; dd++) {
            int d = seg*128 + dd;
            s = fmaf(xsL[d], ld1<BF16>(Wth, (size_t)d*K_ + k), s);
        }
        red[tid] = s;
    }
    __syncthreads();

    if (tid < 64) {
        float s = red[tid] + red[64 + tid] + red[128 + tid] + red[192 + tid];
        float ang = 3.14159265358979323846f * (s + 2048.0f * ld1<BF16>(bth, tid));
        cosL[tid] = cosf(ang);
        sinL[tid] = sinf(ang);
    }
    __syncthreads();

    if (tid < 2) {
        const int j = tid;
        float s = ld1<BF16>(bpar, j);
        for (int k = 0; k < 64; k++) {
            s = fmaf(cosL[k], ld1<BF16>(Wpar, k*2 + j), s);
            s = fmaf(sinL[k], ld1<BF16>(Wpar, (64 + k)*2 + j), s);
        }
        if (BF16) ((u16*)out)[b*2 + j] = f2bf(s);
        else      ((float*)out)[b*2 + j] = s;
    }
}

// ---------------------------------------------------------------------------
// old single-block parity (fallback when workspace is tiny)
// ---------------------------------------------------------------------------
template<bool BF16>
__global__ __launch_bounds__(256) void parity_kernel(
    const void* __restrict__ x, const void* __restrict__ Wth, const void* __restrict__ bth,
    const void* __restrict__ Wpar, const void* __restrict__ bpar, void* __restrict__ out)
{
    if (sniff_is_bf16(x) != BF16) return;

    __shared__ float xsL[512];
    __shared__ float red[256];
    __shared__ float cosL[64], sinL[64];
    const int b = blockIdx.x;
    const int tid = threadIdx.x;

    {
        float s0 = 0.0f, s1 = 0.0f;
        const size_t xb = (size_t)b * T_ * DIN;
        for (int t = 0; t < T_; t++) {
            float a, c2;
            ld2<BF16>(x, xb + (size_t)t*DIN + 2*tid, a, c2);
            s0 += a; s1 += c2;
        }
        xsL[2*tid] = s0; xsL[2*tid + 1] = s1;
    }
    __syncthreads();

    {
        const int k = tid & 63, seg = tid >> 6;
        float s = 0.0f;
        #pragma unroll 8
        for (int dd = 0; dd < 128; dd++) {
            int d = seg*128 + dd;
            s = fmaf(xsL[d], ld1<BF16>(Wth, (size_t)d*K_ + k), s);
        }
        red[tid] = s;
    }
    __syncthreads();

    if (tid < 64) {
        float s = red[tid] + red[64 + tid] + red[128 + tid] + red[192 + tid];
        float ang = 3.14159265358979323846f * (s + 2048.0f * ld1<BF16>(bth, tid));
        cosL[tid] = cosf(ang);
        sinL[tid] = sinf(ang);
    }
    __syncthreads();

    if (tid < 2) {
        const int j = tid;
        float s = ld1<BF16>(bpar, j);
        for (int k = 0; k < 64; k++) {
            s = fmaf(cosL[k], ld1<BF16>(Wpar, k*2 + j), s);
            s = fmaf(sinL[k], ld1<BF16>(Wpar, (64 + k)*2 + j), s);
        }
        if (BF16) ((u16*)out)[b*2 + j] = f2bf(s);
        else      ((float*)out)[b*2 + j] = s;
    }
}

extern "C" void kernel_launch(void* const* d_in, const int* in_sizes, int n_in,
                              void* d_out, int out_size, void* d_ws, size_t ws_size,
                              hipStream_t stream)
{
    const void* x     = d_in[0];
    const void* Wth   = d_in[1];
    const void* bth   = d_in[2];
    const void* Wlam  = d_in[3];
    const void* blam  = d_in[4];
    const void* Wdelt = d_in[5];
    const void* bdelt = d_in[6];
    const void* Winp  = d_in[7];
    const void* binp  = d_in[8];
    const void* Wpar  = d_in[9];
    const void* bpar  = d_in[10];
    const void* Wadd  = d_in[11];
    const void* badd  = d_in[12];

    const bool ws_col  = ws_size >= (size_t)WS_COL_FLOATS * 4;
    const bool ws_w    = ws_size >= (size_t)WS_W_OFF_F * 4 + (size_t)WS_W_PLANE_U32 * 2 * 4;
    const bool ws_full = ws_size >= (size_t)WS_FULL_BYTES;
    float* ws  = (float*)d_ws;
    u32*   wsw = (u32*)((char*)d_ws + WS_WFRAG_OFF_B);
    u32*   wsx = (u32*)((char*)d_ws + WS_XFRAG_OFF_B);

    zero_accum_kernel<<<1, 64, 0, stream>>>(x, d_out);

    // bf16 path: MFMA kernel (sniff-guarded; exits fast on fp32 inputs)
    fused_ssm_mfma_bf16<<<B_*16, 256, 0, stream>>>(
        x, Wlam, blam, Wdelt, bdelt, Winp, binp, Wadd, d_out);

    // fp32 path, tiered by workspace size
    if (ws_full) {
        convert_w_frag_kernel<<<256, 256, 0, stream>>>(x, Wlam, Wdelt, Winp, wsw);
        convert_x_kernel<<<8192, 256, 0, stream>>>(x, wsx);
        fused_ssm_mfma_fp32_full<<<B_*16, 256, 0, stream>>>(
            x, blam, bdelt, binp, Wadd, wsw, wsx, d_out);
    } else if (ws_w) {
        convert_w_kernel<<<768, 256, 0, stream>>>(x, Wlam, Wdelt, Winp, ws);
        fused_ssm_mfma_fp32_ws6<<<B_*16, 256, 0, stream>>>(
            x, blam, bdelt, binp, Wadd, ws, d_out);
    } else {
        fused_ssm_kernel<false><<<B_*MT, 256, 0, stream>>>(
            x, Wlam, blam, Wdelt, bdelt, Winp, binp, Wadd, d_out);
    }

    add_finalize_kernel<true ><<<1, 64, 0, stream>>>(x, badd, d_out);
    add_finalize_kernel<false><<<1, 64, 0, stream>>>(x, badd, d_out);

    if (ws_col) {
        colsum_zero_kernel<<<64, 256, 0, stream>>>(ws);
        parity_colsum_kernel<true ><<<256, 256, 0, stream>>>(x, ws);
        parity_colsum_kernel<false><<<256, 256, 0, stream>>>(x, ws);
        parity_finish_kernel<true ><<<B_, 256, 0, stream>>>(x, ws, Wth, bth, Wpar, bpar, d_out);
        parity_finish_kernel<false><<<B_, 256, 0, stream>>>(x, ws, Wth, bth, Wpar, bpar, d_out);
    } else {
        parity_kernel<true ><<<B_, 256, 0, stream>>>(x, Wth, bth, Wpar, bpar, d_out);
        parity_kernel<false><<<B_, 256, 0, stream>>>(x, Wth, bth, Wpar, bpar, d_out);
    }
}

// Round 9
// 1131.166 us; speedup vs baseline: 1.0062x; 1.0062x over previous
//
#include <hip/hip_runtime.h>
#include <hip/hip_bf16.h>

#define B_   32
#define T_   2048
#define DIN  512
#define DM   1024
#define K_   64
#define BT   64
#define NC   (T_/BT)    // 32 chunks
#define MT   (DM/64)    // 16 m-tiles
#define LDSTR 68        // padded LDS row stride (floats)

typedef unsigned short u16;
typedef unsigned int   u32;

__device__ __forceinline__ float bf2f(u16 h) {
    return __uint_as_float(((u32)h) << 16);
}
__device__ __forceinline__ void bf2x2(u32 w, float& lo, float& hi) {
    lo = __uint_as_float(w << 16);
    hi = __uint_as_float(w & 0xffff0000u);
}
__device__ __forceinline__ u16 f2bf(float f) {   // round-to-nearest-even
    u32 u = __float_as_uint(f);
    u += 0x7fffu + ((u >> 16) & 1u);
    return (u16)(u >> 16);
}
__device__ __forceinline__ float softplusf(float z) {
    return fmaxf(z, 0.0f) + log1pf(expf(-fabsf(z)));
}

// async global->LDS, 16B per lane. Global src is PER-LANE (pass base+lane*16B);
// LDS dest is WAVE-UNIFORM base (HW adds lane*16). [guide §5, m97/m104]
__device__ __forceinline__ void gll16(const u32* g, unsigned char* l) {
    __builtin_amdgcn_global_load_lds(
        (const __attribute__((address_space(1))) u32*)g,
        (__attribute__((address_space(3))) u32*)l,
        16, 0, 0);
}

// ---- dtype-agnostic loaders -------------------------------------------------
template<bool BF16>
__device__ __forceinline__ float ld1(const void* p, size_t i) {
    if (BF16) return bf2f(((const u16*)p)[i]);
    else      return ((const float*)p)[i];
}
template<bool BF16>
__device__ __forceinline__ void ld2(const void* p, size_t i, float& a, float& b) {
    if (BF16) { u32 w = *(const u32*)((const u16*)p + i); bf2x2(w, a, b); }
    else      { float2 v = *(const float2*)((const float*)p + i); a = v.x; b = v.y; }
}
template<bool BF16>
__device__ __forceinline__ void ld8(const void* p, size_t i, float* a) {
    if (BF16) {
        uint4 v = *(const uint4*)((const u16*)p + i);
        bf2x2(v.x, a[0], a[1]); bf2x2(v.y, a[2], a[3]);
        bf2x2(v.z, a[4], a[5]); bf2x2(v.w, a[6], a[7]);
    } else {
        float4 v0 = *(const float4*)((const float*)p + i);
        float4 v1 = *(const float4*)((const float*)p + i + 4);
        a[0]=v0.x; a[1]=v0.y; a[2]=v0.z; a[3]=v0.w;
        a[4]=v1.x; a[5]=v1.y; a[6]=v1.z; a[7]=v1.w;
    }
}

// ---- device-side dtype sniff (block-uniform; needs blockDim.x >= 64) --------
__device__ __forceinline__ bool sniff_is_bf16(const void* xraw) {
    __shared__ int flag_s;
    if (threadIdx.x < 64) {
        u16 w = ((const u16*)xraw)[threadIdx.x];
        float av = fabsf(bf2f(w));
        bool plausible = (av == 0.0f) || (av >= 9.094947e-13f && av <= 64.0f);
        unsigned long long m = __ballot(plausible ? 1 : 0);
        if (threadIdx.x == 0) flag_s = (__popcll(m) >= 56) ? 1 : 0;
    }
    __syncthreads();
    return flag_s != 0;
}

// ---------------------------------------------------------------------------
// zero-init the fp32 accumulator region inside d_out.
// ---------------------------------------------------------------------------
__global__ __launch_bounds__(64) void zero_accum_kernel(const void* x, void* out) {
    bool isbf = sniff_is_bf16(x);
    float* outf = (float*)out;
    if (threadIdx.x < 32) {
        if (isbf) outf[threadIdx.x] = 0.0f;
        else      outf[64 + threadIdx.x] = 0.0f;
    }
}

// ===========================================================================
// Shared MFMA machinery (layouts HW-validated in R1/R2).
// ===========================================================================
typedef __attribute__((ext_vector_type(8)))  short bf16x8;   // 8 bf16 = 4 VGPR
typedef __attribute__((ext_vector_type(16))) float f32x16;   // 32x32 acc

#define TCH 128          // t rows per chunk
#define NCH (T_/TCH)     // 16 chunks
#define A_OFF  0
#define W_OFF  16384
#define AL_OFF 0         // alphaS: 128x64 f32 = 32KB (scan phase)
#define DR_OFF 32768     // driveS: 128x64 f32 = 32KB (scan phase)

// workspace layout (bytes):
//   [0, 64K)                 : parity column-sum accumulators (32 x 512 f32)
//   [64K, 64K+6M)            : W frags (full path) OR W planes (R2 mid path)
//   [64K+6M, 64K+6M+128M)    : X frags (full path only)
#define WS_COL_FLOATS  16384
#define WS_W_OFF_F     16384
#define WS_W_PLANE_U32 (3*256*1024)
#define WS_WFRAG_OFF_B 65536ULL
#define WS_WFRAG_BYTES (16ULL*16*24*1024)          // 6 MiB
#define WS_XFRAG_OFF_B (WS_WFRAG_OFF_B + WS_WFRAG_BYTES)
#define WS_XFRAG_BYTES (32ULL*16*16*16*1024)       // 128 MiB
#define WS_FULL_BYTES  (WS_XFRAG_OFF_B + WS_XFRAG_BYTES)

// ---------------------------------------------------------------------------
// bf16-path fused SSM on MFMA — UNCHANGED (hardware-validated, not timed).
// ---------------------------------------------------------------------------
#define KC  64
__global__ __launch_bounds__(256, 2) void fused_ssm_mfma_bf16(
    const void* __restrict__ x,
    const void* __restrict__ Wlam, const void* __restrict__ blam,
    const void* __restrict__ Wdelt, const void* __restrict__ bdelt,
    const void* __restrict__ Winp, const void* __restrict__ binp,
    const void* __restrict__ Wadd,
    void* __restrict__ out)
{
    __shared__ __align__(16) unsigned char LDS[65536];

    const int tid = threadIdx.x;

    {   // inline dtype sniff (flag in LDS[0]); bf16 only proceeds
        int* flag = (int*)LDS;
        if (tid < 64) {
            u16 w0 = ((const u16*)x)[tid];
            float av = fabsf(bf2f(w0));
            bool plausible = (av == 0.0f) || (av >= 9.094947e-13f && av <= 64.0f);
            unsigned long long m = __ballot(plausible ? 1 : 0);
            if (tid == 0) *flag = (__popcll(m) >= 56) ? 1 : 0;
        }
        __syncthreads();
        int isbf = *flag;
        __syncthreads();
        if (!isbf) return;
    }

    const int swz = (blockIdx.x & 7) * 64 + (blockIdx.x >> 3);
    const int mg  = swz & 15;
    const int b   = swz >> 4;
    const int m0  = mg * 64;

    const int lane = tid & 63;
    const int w    = tid >> 6;
    const int p    = w >> 1;
    const int h    = w & 1;
    const int lr   = lane & 31;
    const int lg   = lane >> 5;

    const int colg = m0 + h*32 + lr;
    const float bL = bf2f(((const u16*)blam )[colg]);
    const float bD = bf2f(((const u16*)bdelt)[colg]);
    const float bI = bf2f(((const u16*)binp )[colg]);

    float* alphaS = (float*)(LDS + AL_OFF);
    float* driveS = (float*)(LDS + DR_OFF);

    float scarry = 0.0f;

    #pragma unroll 1
    for (int c = 0; c < NCH; c++) {
        f32x16 aL0, aL1, aD0, aD1, aI0, aI1;
        #pragma unroll
        for (int r = 0; r < 16; r++) {
            aL0[r] = bL; aL1[r] = bL;
            aD0[r] = bD; aD1[r] = bD;
            aI0[r] = bI; aI1[r] = bI;
        }

        #pragma unroll 1
        for (int kc = 0; kc < DIN/KC; kc++) {
            {
                const int t_l  = tid >> 1;
                const int half = tid & 1;
                const u16* xp = (const u16*)x
                    + ((size_t)b*T_ + (size_t)c*TCH + t_l)*DIN + kc*KC + half*32;
                uint4 v[4];
                v[0] = *(const uint4*)(xp);
                v[1] = *(const uint4*)(xp + 8);
                v[2] = *(const uint4*)(xp + 16);
                v[3] = *(const uint4*)(xp + 24);
                const int tt = t_l >> 5, tr = t_l & 31;
                #pragma unroll
                for (int q = 0; q < 4; q++) {
                    const int o  = half*4 + q;
                    const int ks = o >> 1, g = o & 1;
                    *(uint4*)(LDS + A_OFF + ((tt*4 + ks) << 10) + ((g*32 + tr) << 4)) = v[q];
                }
            }
            #pragma unroll
            for (int i = 0; i < 6; i++) {
                const int f   = w + 4*i;
                const int nt  = f >> 2, ks = f & 3;
                const int hh  = (nt >= 3) ? 1 : 0;
                const int mat = nt - 3*hh;
                const u16* Wp = (const u16*)(mat == 0 ? Wlam : (mat == 1 ? Wdelt : Winp));
                const size_t base = (size_t)(kc*KC + ks*16 + lg*8)*DM + (size_t)(m0 + hh*32 + lr);
                u32 e0 = Wp[base        ];
                u32 e1 = Wp[base +   DM ];
                u32 e2 = Wp[base + 2*DM ];
                u32 e3 = Wp[base + 3*DM ];
                u32 e4 = Wp[base + 4*DM ];
                u32 e5 = Wp[base + 5*DM ];
                u32 e6 = Wp[base + 6*DM ];
                u32 e7 = Wp[base + 7*DM ];
                uint4 pk;
                pk.x = e0 | (e1 << 16);
                pk.y = e2 | (e3 << 16);
                pk.z = e4 | (e5 << 16);
                pk.w = e6 | (e7 << 16);
                *(uint4*)(LDS + W_OFF + (f << 10) + (lane << 4)) = pk;
            }
            __syncthreads();

            #pragma unroll
            for (int ks = 0; ks < 4; ks++) {
                bf16x8 a0 = *(const bf16x8*)(LDS + A_OFF + (((2*p    )*4 + ks) << 10) + (lane << 4));
                bf16x8 a1 = *(const bf16x8*)(LDS + A_OFF + (((2*p + 1)*4 + ks) << 10) + (lane << 4));
                bf16x8 vL = *(const bf16x8*)(LDS + W_OFF + (((h*3 + 0)*4 + ks) << 10) + (lane << 4));
                bf16x8 vD = *(const bf16x8*)(LDS + W_OFF + (((h*3 + 1)*4 + ks) << 10) + (lane << 4));
                bf16x8 vI = *(const bf16x8*)(LDS + W_OFF + (((h*3 + 2)*4 + ks) << 10) + (lane << 4));
                aL0 = __builtin_amdgcn_mfma_f32_32x32x16_bf16(a0, vL, aL0, 0, 0, 0);
                aL1 = __builtin_amdgcn_mfma_f32_32x32x16_bf16(a1, vL, aL1, 0, 0, 0);
                aD0 = __builtin_amdgcn_mfma_f32_32x32x16_bf16(a0, vD, aD0, 0, 0, 0);
                aD1 = __builtin_amdgcn_mfma_f32_32x32x16_bf16(a1, vD, aD1, 0, 0, 0);
                aI0 = __builtin_amdgcn_mfma_f32_32x32x16_bf16(a0, vI, aI0, 0, 0, 0);
                aI1 = __builtin_amdgcn_mfma_f32_32x32x16_bf16(a1, vI, aI1, 0, 0, 0);
            }
            __syncthreads();
        }

        #pragma unroll
        for (int tt2 = 0; tt2 < 2; tt2++) {
            #pragma unroll
            for (int r = 0; r < 16; r++) {
                const float zl = tt2 ? aL1[r] : aL0[r];
                const float zd = tt2 ? aD1[r] : aD0[r];
                const float zi = tt2 ? aI1[r] : aI0[r];
                const float lam = softplusf(zl);
                const float dl  = softplusf(zd);
                const float av  = expf(-dl * lam);
                const float dv  = dl * zi;
                const int t_loc = (2*p + tt2)*32 + (r & 3) + 8*(r >> 2) + 4*lg;
                const int m_loc = h*32 + lr;
                alphaS[t_loc*64 + m_loc] = av;
                driveS[t_loc*64 + m_loc] = dv;
            }
        }
        __syncthreads();

        if (tid < 64) {
            float s = scarry;
            #pragma unroll 8
            for (int t = 0; t < TCH; t++)
                s = fmaf(alphaS[t*64 + tid], s, driveS[t*64 + tid]);
            scarry = s;
        }
        __syncthreads();
    }

    if (tid < 64) {
        float partial = scarry * bf2f(((const u16*)Wadd)[m0 + tid]);
        #pragma unroll
        for (int off = 32; off > 0; off >>= 1)
            partial += __shfl_down(partial, off, 64);
        if (tid == 0)
            atomicAdd(&((float*)out)[b], partial);
    }
}

// ---------------------------------------------------------------------------
// R2 mid-path precursor — W planes, pair-packed (kept as fallback).
// ---------------------------------------------------------------------------
__global__ __launch_bounds__(256) void convert_w_kernel(
    const void* __restrict__ x,
    const void* __restrict__ Wlam, const void* __restrict__ Wdelt,
    const void* __restrict__ Winp, float* __restrict__ ws)
{
    if (sniff_is_bf16(x)) return;
    const int mat = blockIdx.x >> 8;
    const int kp  = blockIdx.x & 255;
    const float* Wp = (mat == 0) ? (const float*)Wlam
                    : (mat == 1) ? (const float*)Wdelt : (const float*)Winp;
    u32* whi = (u32*)(ws + WS_W_OFF_F);
    u32* wlo = whi + WS_W_PLANE_U32;
    const size_t ro = (size_t)(2*kp)*DM;
    const size_t wo = ((size_t)mat*256 + kp)*DM;
    #pragma unroll
    for (int mm = 0; mm < 4; mm++) {
        const int m = mm*256 + threadIdx.x;
        float a0 = Wp[ro + m];
        float a1 = Wp[ro + DM + m];
        u16 h0 = f2bf(a0), h1 = f2bf(a1);
        float l0 = a0 - bf2f(h0);
        float l1 = a1 - bf2f(h1);
        whi[wo + m] = (u32)h0 | ((u32)h1 << 16);
        wlo[wo + m] = (__float_as_uint(l0) >> 16) | (__float_as_uint(l1) & 0xffff0000u);
    }
}

// ---------------------------------------------------------------------------
// W -> frag-linear split-bf16: wsw[mg][kc][f(24)][1KB].
// ---------------------------------------------------------------------------
__global__ __launch_bounds__(256) void convert_w_frag_kernel(
    const void* __restrict__ x,
    const void* __restrict__ Wlam, const void* __restrict__ Wdelt,
    const void* __restrict__ Winp, u32* __restrict__ wsw)
{
    if (sniff_is_bf16(x)) return;
    const int kc = blockIdx.x & 15;
    const int mg = blockIdx.x >> 4;
    const int m0 = mg*64;
    u32* dst = wsw + (size_t)(mg*16 + kc) * 6144;   // 24*256 u32
    #pragma unroll
    for (int i = 0; i < 6; i++) {
        const int u = threadIdx.x + 256*i;   // 0..1535
        const int f = u >> 6;                // 0..23
        const int l = u & 63;
        const int hl = f & 1, ks = (f >> 1) & 1, nt = f >> 2;
        const int hh = nt / 3, mat = nt % 3;
        const float* Wp = (mat == 0) ? (const float*)Wlam
                        : (mat == 1) ? (const float*)Wdelt : (const float*)Winp;
        const int lr = l & 31, lg = l >> 5;
        const int kp0 = kc*16 + ks*8 + lg*4;
        const int m = m0 + hh*32 + lr;
        u32 q4[4];
        #pragma unroll
        for (int q = 0; q < 4; q++) {
            float a0 = Wp[(size_t)(2*(kp0+q)    )*DM + m];
            float a1 = Wp[(size_t)(2*(kp0+q) + 1)*DM + m];
            u16 h0 = f2bf(a0), h1 = f2bf(a1);
            if (hl == 0) {
                q4[q] = (u32)h0 | ((u32)h1 << 16);
            } else {
                float l0 = a0 - bf2f(h0);
                float l1 = a1 - bf2f(h1);
                q4[q] = (__float_as_uint(l0) >> 16) | (__float_as_uint(l1) & 0xffff0000u);
            }
        }
        *(uint4*)(dst + f*256 + l*4) = make_uint4(q4[0], q4[1], q4[2], q4[3]);
    }
}

// ---------------------------------------------------------------------------
// x -> frag-linear split-bf16: wsx[b][c][kc][f(16)][1KB].
// Identical arithmetic to the R2 in-kernel conversion (bit-identical result).
// ---------------------------------------------------------------------------
#define KC2 32
__global__ __launch_bounds__(256) void convert_x_kernel(
    const void* __restrict__ x, u32* __restrict__ wsx)
{
    if (sniff_is_bf16(x)) return;
    const int kc = blockIdx.x & 15;
    const int c  = (blockIdx.x >> 4) & 15;
    const int b  = blockIdx.x >> 8;
    const int tid = threadIdx.x;
    const int t_l  = tid >> 1;          // 0..127
    const int half = tid & 1;           // = ks
    const float* xp = (const float*)x
        + ((size_t)b*T_ + (size_t)c*TCH + t_l)*DIN + kc*KC2 + half*16;
    float vv[16];
    *(float4*)(vv)      = *(const float4*)(xp);
    *(float4*)(vv + 4)  = *(const float4*)(xp + 4);
    *(float4*)(vv + 8)  = *(const float4*)(xp + 8);
    *(float4*)(vv + 12) = *(const float4*)(xp + 12);
    u32 hi[8], lo[8];
    #pragma unroll
    for (int q = 0; q < 8; q++) {
        const float a0 = vv[2*q], a1 = vv[2*q+1];
        const u16 h0 = f2bf(a0), h1 = f2bf(a1);
        hi[q] = (u32)h0 | ((u32)h1 << 16);
        const float l0 = a0 - bf2f(h0);
        const float l1 = a1 - bf2f(h1);
        lo[q] = (__float_as_uint(l0) >> 16) | (__float_as_uint(l1) & 0xffff0000u);
    }
    u32* dst = wsx + ((((size_t)b*16 + c)*16 + kc) << 12);   // *4096 u32
    const int tt = t_l >> 5, tr = t_l & 31;
    const int fb = (tt*2 + half)*2;
    *(uint4*)(dst + fb*256     + (0*32 + tr)*4) = make_uint4(hi[0],hi[1],hi[2],hi[3]);
    *(uint4*)(dst + fb*256     + (1*32 + tr)*4) = make_uint4(hi[4],hi[5],hi[6],hi[7]);
    *(uint4*)(dst + (fb+1)*256 + (0*32 + tr)*4) = make_uint4(lo[0],lo[1],lo[2],lo[3]);
    *(uint4*)(dst + (fb+1)*256 + (1*32 + tr)*4) = make_uint4(lo[4],lo[5],lo[6],lo[7]);
}

// ---------------------------------------------------------------------------
// fp32-path fused SSM, full-workspace variant (R9: gll16 double-buffer with
// COUNTED vmcnt across raw s_barriers — T4. Per kc:
//   s_barrier (WAR: nxt readers done) -> issue 10 gll16 into nxt ->
//   s_waitcnt vmcnt(10) (cur landed for this wave; new 10 stay in flight) ->
//   sched_barrier(0) -> s_barrier (RAW: everyone's cur landed) -> MFMA(cur).
// vmcnt(0) only at last kc of each chunk. __syncthreads() drain happens once
// per chunk before the activation phase. MFMA/activation/scan identical to
// R8 (bit-identical numerics).
// ---------------------------------------------------------------------------
#define STG_B 40960   // one staging buffer: A 16KB @ +0, W 24KB @ +16384
__global__ __launch_bounds__(256, 2) void fused_ssm_mfma_fp32_full(
    const void* __restrict__ x,
    const void* __restrict__ blam, const void* __restrict__ bdelt,
    const void* __restrict__ binp, const void* __restrict__ Wadd,
    const u32* __restrict__ wsw, const u32* __restrict__ wsx,
    void* __restrict__ out)
{
    __shared__ __align__(16) unsigned char LDS[2*STG_B];   // 80 KB

    const int tid = threadIdx.x;

    {   // inline dtype sniff; fp32 only proceeds
        int* flag = (int*)LDS;
        if (tid < 64) {
            u16 w0 = ((const u16*)x)[tid];
            float av = fabsf(bf2f(w0));
            bool plausible = (av == 0.0f) || (av >= 9.094947e-13f && av <= 64.0f);
            unsigned long long m = __ballot(plausible ? 1 : 0);
            if (tid == 0) *flag = (__popcll(m) >= 56) ? 1 : 0;
        }
        __syncthreads();
        int isbf = *flag;
        __syncthreads();
        if (isbf) return;
    }

    const int swz = (blockIdx.x & 7) * 64 + (blockIdx.x >> 3);
    const int mg  = swz & 15;
    const int b   = swz >> 4;
    const int m0  = mg * 64;

    const int lane = tid & 63;
    const int w    = tid >> 6;
    const int p    = w >> 1;
    const int h    = w & 1;
    const int lr   = lane & 31;
    const int lg   = lane >> 5;

    const int colg = m0 + h*32 + lr;
    const float bL = ((const float*)blam )[colg];
    const float bD = ((const float*)bdelt)[colg];
    const float bI = ((const float*)binp )[colg];

    float* alphaS = (float*)(LDS + AL_OFF);
    float* driveS = (float*)(LDS + DR_OFF);

    // wave-local staging sources (per-lane global addresses; u32 units)
    const u32* gwB = wsw + (size_t)(mg*16)*6144 + (size_t)(w*6)*256 + (size_t)lane*4;

    float scarry = 0.0f;

    #pragma unroll 1
    for (int c = 0; c < NCH; c++) {
        f32x16 aL0, aL1, aD0, aD1, aI0, aI1;
        #pragma unroll
        for (int r = 0; r < 16; r++) {
            aL0[r] = bL; aL1[r] = bL;
            aD0[r] = bD; aD1[r] = bD;
            aI0[r] = bI; aI1[r] = bI;
        }

        const u32* gaB = wsx + ((((size_t)b*16 + c)*16) << 12)
                             + (size_t)(w*4)*256 + (size_t)lane*4;

        // ---- chunk prologue: issue kc=0 loads into buf0 (NO wait here;
        //      kc=0's vmcnt(10) covers them). LDS buf0 is free: previous
        //      chunk's scan finished at its trailing __syncthreads.
        {
            unsigned char* la = LDS + (w*4)*1024;
            gll16(gaB,        la);
            gll16(gaB + 256,  la + 1024);
            gll16(gaB + 512,  la + 2048);
            gll16(gaB + 768,  la + 3072);
            unsigned char* lw = LDS + 16384 + (w*6)*1024;
            gll16(gwB,         lw);
            gll16(gwB + 256,   lw + 1024);
            gll16(gwB + 512,   lw + 2048);
            gll16(gwB + 768,   lw + 3072);
            gll16(gwB + 1024,  lw + 4096);
            gll16(gwB + 1280,  lw + 5120);
        }

        #pragma unroll 1
        for (int kc = 0; kc < DIN/KC2; kc++) {
            unsigned char* cur = LDS + (kc & 1)*STG_B;
            unsigned char* nxt = LDS + ((kc + 1) & 1)*STG_B;

            // ---- barrier1 (WAR): all waves finished reading nxt (it was
            //      cur of kc-1; their MFMAs precede this in program order)
            __builtin_amdgcn_s_barrier();

            // ---- issue next-kc gll16 into nxt (stay in flight across the
            //      counted wait, barrier2, and the whole MFMA phase)
            if (kc < DIN/KC2 - 1) {
                const u32* ga = gaB + (size_t)(kc + 1)*4096;
                const u32* gw = gwB + (size_t)(kc + 1)*6144;
                unsigned char* la = nxt + (w*4)*1024;
                gll16(ga,        la);
                gll16(ga + 256,  la + 1024);
                gll16(ga + 512,  la + 2048);
                gll16(ga + 768,  la + 3072);
                unsigned char* lw = nxt + 16384 + (w*6)*1024;
                gll16(gw,         lw);
                gll16(gw + 256,   lw + 1024);
                gll16(gw + 512,   lw + 2048);
                gll16(gw + 768,   lw + 3072);
                gll16(gw + 1024,  lw + 4096);
                gll16(gw + 1280,  lw + 5120);
                // counted wait: oldest 10 (cur's loads) landed; new 10 remain
                asm volatile("s_waitcnt vmcnt(10)" ::: "memory");
            } else {
                // last kc of chunk: nothing new in flight afterwards
                asm volatile("s_waitcnt vmcnt(0)" ::: "memory");
            }
            __builtin_amdgcn_sched_barrier(0);

            // ---- barrier2 (RAW): every wave passed its vmcnt -> all of
            //      cur's frags are resident
            __builtin_amdgcn_s_barrier();

            // ---- MFMA on current buffer: 2 K-steps x (2 tt x 3 mats x 3)
            #pragma unroll
            for (int ks = 0; ks < 2; ks++) {
                const int fa0 = ((2*p    )*2 + ks)*2;
                const int fa1 = ((2*p + 1)*2 + ks)*2;
                const int fL  = ((h*3 + 0)*2 + ks)*2;
                const int fD  = ((h*3 + 1)*2 + ks)*2;
                const int fI  = ((h*3 + 2)*2 + ks)*2;
                bf16x8 a0h = *(const bf16x8*)(cur + (fa0     << 10) + (lane << 4));
                bf16x8 a0l = *(const bf16x8*)(cur + ((fa0+1) << 10) + (lane << 4));
                bf16x8 a1h = *(const bf16x8*)(cur + (fa1     << 10) + (lane << 4));
                bf16x8 a1l = *(const bf16x8*)(cur + ((fa1+1) << 10) + (lane << 4));
                bf16x8 vLh = *(const bf16x8*)(cur + 16384 + (fL      << 10) + (lane << 4));
                bf16x8 vLl = *(const bf16x8*)(cur + 16384 + ((fL+1)  << 10) + (lane << 4));
                bf16x8 vDh = *(const bf16x8*)(cur + 16384 + (fD      << 10) + (lane << 4));
                bf16x8 vDl = *(const bf16x8*)(cur + 16384 + ((fD+1)  << 10) + (lane << 4));
                bf16x8 vIh = *(const bf16x8*)(cur + 16384 + (fI      << 10) + (lane << 4));
                bf16x8 vIl = *(const bf16x8*)(cur + 16384 + ((fI+1)  << 10) + (lane << 4));
                aL0 = __builtin_amdgcn_mfma_f32_32x32x16_bf16(a0h, vLh, aL0, 0, 0, 0);
                aL0 = __builtin_amdgcn_mfma_f32_32x32x16_bf16(a0h, vLl, aL0, 0, 0, 0);
                aL0 = __builtin_amdgcn_mfma_f32_32x32x16_bf16(a0l, vLh, aL0, 0, 0, 0);
                aL1 = __builtin_amdgcn_mfma_f32_32x32x16_bf16(a1h, vLh, aL1, 0, 0, 0);
                aL1 = __builtin_amdgcn_mfma_f32_32x32x16_bf16(a1h, vLl, aL1, 0, 0, 0);
                aL1 = __builtin_amdgcn_mfma_f32_32x32x16_bf16(a1l, vLh, aL1, 0, 0, 0);
                aD0 = __builtin_amdgcn_mfma_f32_32x32x16_bf16(a0h, vDh, aD0, 0, 0, 0);
                aD0 = __builtin_amdgcn_mfma_f32_32x32x16_bf16(a0h, vDl, aD0, 0, 0, 0);
                aD0 = __builtin_amdgcn_mfma_f32_32x32x16_bf16(a0l, vDh, aD0, 0, 0, 0);
                aD1 = __builtin_amdgcn_mfma_f32_32x32x16_bf16(a1h, vDh, aD1, 0, 0, 0);
                aD1 = __builtin_amdgcn_mfma_f32_32x32x16_bf16(a1h, vDl, aD1, 0, 0, 0);
                aD1 = __builtin_amdgcn_mfma_f32_32x32x16_bf16(a1l, vDh, aD1, 0, 0, 0);
                aI0 = __builtin_amdgcn_mfma_f32_32x32x16_bf16(a0h, vIh, aI0, 0, 0, 0);
                aI0 = __builtin_amdgcn_mfma_f32_32x32x16_bf16(a0h, vIl, aI0, 0, 0, 0);
                aI0 = __builtin_amdgcn_mfma_f32_32x32x16_bf16(a0l, vIh, aI0, 0, 0, 0);
                aI1 = __builtin_amdgcn_mfma_f32_32x32x16_bf16(a1h, vIh, aI1, 0, 0, 0);
                aI1 = __builtin_amdgcn_mfma_f32_32x32x16_bf16(a1h, vIl, aI1, 0, 0, 0);
                aI1 = __builtin_amdgcn_mfma_f32_32x32x16_bf16(a1l, vIh, aI1, 0, 0, 0);
            }
        }

        // ---- full join before activation overwrites the staging LDS
        //      (vmcnt is already 0 from the last kc's drain)
        __syncthreads();

        // ---- activation (lane-local) -> alpha/drive in LDS ----
        #pragma unroll
        for (int tt2 = 0; tt2 < 2; tt2++) {
            #pragma unroll
            for (int r = 0; r < 16; r++) {
                const float zl = tt2 ? aL1[r] : aL0[r];
                const float zd = tt2 ? aD1[r] : aD0[r];
                const float zi = tt2 ? aI1[r] : aI0[r];
                const float lam = softplusf(zl);
                const float dl  = softplusf(zd);
                const float av  = expf(-dl * lam);
                const float dv  = dl * zi;
                const int t_loc = (2*p + tt2)*32 + (r & 3) + 8*(r >> 2) + 4*lg;
                const int m_loc = h*32 + lr;
                alphaS[t_loc*64 + m_loc] = av;
                driveS[t_loc*64 + m_loc] = dv;
            }
        }
        __syncthreads();

        // ---- in-chunk scan, one thread per m column ----
        if (tid < 64) {
            float s = scarry;
            #pragma unroll 8
            for (int t = 0; t < TCH; t++)
                s = fmaf(alphaS[t*64 + tid], s, driveS[t*64 + tid]);
            scarry = s;
        }
        __syncthreads();
    }

    if (tid < 64) {
        float partial = scarry * ((const float*)Wadd)[m0 + tid];
        #pragma unroll
        for (int off = 32; off > 0; off >>= 1)
            partial += __shfl_down(partial, off, 64);
        if (tid == 0)
            atomicAdd(&((float*)out)[64 + b], partial);
    }
}

// ---------------------------------------------------------------------------
// R2 fp32-path fused SSM (mid-workspace fallback) — unchanged.
// ---------------------------------------------------------------------------
__global__ __launch_bounds__(256, 2) void fused_ssm_mfma_fp32_ws6(
    const void* __restrict__ x,
    const void* __restrict__ blam, const void* __restrict__ bdelt,
    const void* __restrict__ binp, const void* __restrict__ Wadd,
    const float* __restrict__ ws,
    void* __restrict__ out)
{
    __shared__ __align__(16) unsigned char LDS[65536];

    const int tid = threadIdx.x;

    {
        int* flag = (int*)LDS;
        if (tid < 64) {
            u16 w0 = ((const u16*)x)[tid];
            float av = fabsf(bf2f(w0));
            bool plausible = (av == 0.0f) || (av >= 9.094947e-13f && av <= 64.0f);
            unsigned long long m = __ballot(plausible ? 1 : 0);
            if (tid == 0) *flag = (__popcll(m) >= 56) ? 1 : 0;
        }
        __syncthreads();
        int isbf = *flag;
        __syncthreads();
        if (isbf) return;
    }

    const u32* whi = (const u32*)(ws + WS_W_OFF_F);
    const u32* wlo = whi + WS_W_PLANE_U32;

    const int swz = (blockIdx.x & 7) * 64 + (blockIdx.x >> 3);
    const int mg  = swz & 15;
    const int b   = swz >> 4;
    const int m0  = mg * 64;

    const int lane = tid & 63;
    const int w    = tid >> 6;
    const int p    = w >> 1;
    const int h    = w & 1;
    const int lr   = lane & 31;
    const int lg   = lane >> 5;

    const int colg = m0 + h*32 + lr;
    const float bL = ((const float*)blam )[colg];
    const float bD = ((const float*)bdelt)[colg];
    const float bI = ((const float*)binp )[colg];

    int fhi_[3], kp0_[3]; size_t wb_[3];
    #pragma unroll
    for (int i = 0; i < 3; i++) {
        const int u2 = w + 4*i;
        const int ks = u2 & 1, mu = u2 >> 1;
        const int mat = mu % 3, hh = mu / 3;
        fhi_[i] = 2*u2;
        kp0_[i] = ks*8 + lg*4;
        wb_[i]  = ((size_t)mat*256)*DM + (size_t)(m0 + hh*32 + lr);
    }

    float* alphaS = (float*)(LDS + AL_OFF);
    float* driveS = (float*)(LDS + DR_OFF);

    float scarry = 0.0f;

    #pragma unroll 1
    for (int c = 0; c < NCH; c++) {
        f32x16 aL0, aL1, aD0, aD1, aI0, aI1;
        #pragma unroll
        for (int r = 0; r < 16; r++) {
            aL0[r] = bL; aL1[r] = bL;
            aD0[r] = bD; aD1[r] = bD;
            aI0[r] = bI; aI1[r] = bI;
        }

        #pragma unroll 1
        for (int kc = 0; kc < DIN/KC2; kc++) {
            {
                const int t_l  = tid >> 1;
                const int half = tid & 1;
                const float* xp = (const float*)x
                    + ((size_t)b*T_ + (size_t)c*TCH + t_l)*DIN + kc*KC2 + half*16;
                float vv[16];
                *(float4*)(vv)      = *(const float4*)(xp);
                *(float4*)(vv + 4)  = *(const float4*)(xp + 4);
                *(float4*)(vv + 8)  = *(const float4*)(xp + 8);
                *(float4*)(vv + 12) = *(const float4*)(xp + 12);
                u32 hi[8], lo[8];
                #pragma unroll
                for (int q = 0; q < 8; q++) {
                    const float a0 = vv[2*q], a1 = vv[2*q+1];
                    const u16 h0 = f2bf(a0), h1 = f2bf(a1);
                    hi[q] = (u32)h0 | ((u32)h1 << 16);
                    const float l0 = a0 - bf2f(h0);
                    const float l1 = a1 - bf2f(h1);
                    lo[q] = (__float_as_uint(l0) >> 16) | (__float_as_uint(l1) & 0xffff0000u);
                }
                const int tt = t_l >> 5, tr = t_l & 31;
                const int fb = (tt*2 + half)*2;
                *(uint4*)(LDS + A_OFF + (fb << 10)     + ((0*32 + tr) << 4)) = make_uint4(hi[0],hi[1],hi[2],hi[3]);
                *(uint4*)(LDS + A_OFF + (fb << 10)     + ((1*32 + tr) << 4)) = make_uint4(hi[4],hi[5],hi[6],hi[7]);
                *(uint4*)(LDS + A_OFF + ((fb+1) << 10) + ((0*32 + tr) << 4)) = make_uint4(lo[0],lo[1],lo[2],lo[3]);
                *(uint4*)(LDS + A_OFF + ((fb+1) << 10) + ((1*32 + tr) << 4)) = make_uint4(lo[4],lo[5],lo[6],lo[7]);
            }
            #pragma unroll
            for (int i = 0; i < 3; i++) {
                const size_t base = wb_[i] + (size_t)(kc*16 + kp0_[i])*DM;
                uint4 ph, pl;
                ph.x = whi[base]; ph.y = whi[base + DM]; ph.z = whi[base + 2*DM]; ph.w = whi[base + 3*DM];
                pl.x = wlo[base]; pl.y = wlo[base + DM]; pl.z = wlo[base + 2*DM]; pl.w = wlo[base + 3*DM];
                *(uint4*)(LDS + W_OFF + (fhi_[i] << 10)       + (lane << 4)) = ph;
                *(uint4*)(LDS + W_OFF + ((fhi_[i] + 1) << 10) + (lane << 4)) = pl;
            }
            __syncthreads();

            #pragma unroll
            for (int ks = 0; ks < 2; ks++) {
                const int fa0 = ((2*p    )*2 + ks)*2;
                const int fa1 = ((2*p + 1)*2 + ks)*2;
                const int fL  = ((h*3 + 0)*2 + ks)*2;
                const int fD  = ((h*3 + 1)*2 + ks)*2;
                const int fI  = ((h*3 + 2)*2 + ks)*2;
                bf16x8 a0h = *(const bf16x8*)(LDS + A_OFF + (fa0     << 10) + (lane << 4));
                bf16x8 a0l = *(const bf16x8*)(LDS + A_OFF + ((fa0+1) << 10) + (lane << 4));
                bf16x8 a1h = *(const bf16x8*)(LDS + A_OFF + (fa1     << 10) + (lane << 4));
                bf16x8 a1l = *(const bf16x8*)(LDS + A_OFF + ((fa1+1) << 10) + (lane << 4));
                bf16x8 vLh = *(const bf16x8*)(LDS + W_OFF + (fL      << 10) + (lane << 4));
                bf16x8 vLl = *(const bf16x8*)(LDS + W_OFF + ((fL+1)  << 10) + (lane << 4));
                bf16x8 vDh = *(const bf16x8*)(LDS + W_OFF + (fD      << 10) + (lane << 4));
                bf16x8 vDl = *(const bf16x8*)(LDS + W_OFF + ((fD+1)  << 10) + (lane << 4));
                bf16x8 vIh = *(const bf16x8*)(LDS + W_OFF + (fI      << 10) + (lane << 4));
                bf16x8 vIl = *(const bf16x8*)(LDS + W_OFF + ((fI+1)  << 10) + (lane << 4));
                aL0 = __builtin_amdgcn_mfma_f32_32x32x16_bf16(a0h, vLh, aL0, 0, 0, 0);
                aL0 = __builtin_amdgcn_mfma_f32_32x32x16_bf16(a0h, vLl, aL0, 0, 0, 0);
                aL0 = __builtin_amdgcn_mfma_f32_32x32x16_bf16(a0l, vLh, aL0, 0, 0, 0);
                aL1 = __builtin_amdgcn_mfma_f32_32x32x16_bf16(a1h, vLh, aL1, 0, 0, 0);
                aL1 = __builtin_amdgcn_mfma_f32_32x32x16_bf16(a1h, vLl, aL1, 0, 0, 0);
                aL1 = __builtin_amdgcn_mfma_f32_32x32x16_bf16(a1l, vLh, aL1, 0, 0, 0);
                aD0 = __builtin_amdgcn_mfma_f32_32x32x16_bf16(a0h, vDh, aD0, 0, 0, 0);
                aD0 = __builtin_amdgcn_mfma_f32_32x32x16_bf16(a0h, vDl, aD0, 0, 0, 0);
                aD0 = __builtin_amdgcn_mfma_f32_32x32x16_bf16(a0l, vDh, aD0, 0, 0, 0);
                aD1 = __builtin_amdgcn_mfma_f32_32x32x16_bf16(a1h, vDh, aD1, 0, 0, 0);
                aD1 = __builtin_amdgcn_mfma_f32_32x32x16_bf16(a1h, vDl, aD1, 0, 0, 0);
                aD1 = __builtin_amdgcn_mfma_f32_32x32x16_bf16(a1l, vDh, aD1, 0, 0, 0);
                aI0 = __builtin_amdgcn_mfma_f32_32x32x16_bf16(a0h, vIh, aI0, 0, 0, 0);
                aI0 = __builtin_amdgcn_mfma_f32_32x32x16_bf16(a0h, vIl, aI0, 0, 0, 0);
                aI0 = __builtin_amdgcn_mfma_f32_32x32x16_bf16(a0l, vIh, aI0, 0, 0, 0);
                aI1 = __builtin_amdgcn_mfma_f32_32x32x16_bf16(a1h, vIh, aI1, 0, 0, 0);
                aI1 = __builtin_amdgcn_mfma_f32_32x32x16_bf16(a1h, vIl, aI1, 0, 0, 0);
                aI1 = __builtin_amdgcn_mfma_f32_32x32x16_bf16(a1l, vIh, aI1, 0, 0, 0);
            }
            __syncthreads();
        }

        #pragma unroll
        for (int tt2 = 0; tt2 < 2; tt2++) {
            #pragma unroll
            for (int r = 0; r < 16; r++) {
                const float zl = tt2 ? aL1[r] : aL0[r];
                const float zd = tt2 ? aD1[r] : aD0[r];
                const float zi = tt2 ? aI1[r] : aI0[r];
                const float lam = softplusf(zl);
                const float dl  = softplusf(zd);
                const float av  = expf(-dl * lam);
                const float dv  = dl * zi;
                const int t_loc = (2*p + tt2)*32 + (r & 3) + 8*(r >> 2) + 4*lg;
                const int m_loc = h*32 + lr;
                alphaS[t_loc*64 + m_loc] = av;
                driveS[t_loc*64 + m_loc] = dv;
            }
        }
        __syncthreads();

        if (tid < 64) {
            float s = scarry;
            #pragma unroll 8
            for (int t = 0; t < TCH; t++)
                s = fmaf(alphaS[t*64 + tid], s, driveS[t*64 + tid]);
            scarry = s;
        }
        __syncthreads();
    }

    if (tid < 64) {
        float partial = scarry * ((const float*)Wadd)[m0 + tid];
        #pragma unroll
        for (int off = 32; off > 0; off >>= 1)
            partial += __shfl_down(partial, off, 64);
        if (tid == 0)
            atomicAdd(&((float*)out)[64 + b], partial);
    }
}

// ---------------------------------------------------------------------------
// fp32-path fused SSM on VALU — last-resort fallback (no workspace).
// ---------------------------------------------------------------------------
template<bool BF16>
__global__ __launch_bounds__(256) void fused_ssm_kernel(
    const void* __restrict__ x,
    const void* __restrict__ Wlam, const void* __restrict__ blam,
    const void* __restrict__ Wdelt, const void* __restrict__ bdelt,
    const void* __restrict__ Winp, const void* __restrict__ binp,
    const void* __restrict__ Wadd,
    void* __restrict__ out)
{
    if (sniff_is_bf16(x) != BF16) return;

    __shared__ __align__(16) float smem[8704];

    const int mt  = blockIdx.x & 15;
    const int b   = blockIdx.x >> 4;
    const int tid = threadIdx.x;
    const int tx  = tid & 15;
    const int ty  = tid >> 4;

    float bl[4], bd[4], bi[4];
    #pragma unroll
    for (int jj = 0; jj < 4; jj++) {
        int m = mt*64 + tx*4 + jj;
        bl[jj] = ld1<BF16>(blam, m); bd[jj] = ld1<BF16>(bdelt, m); bi[jj] = ld1<BF16>(binp, m);
    }

    float* xsT = smem;
    float* w3  = smem + 32*LDSTR;
    float* alphaS = smem;
    float* driveS = smem + 64*LDSTR;

    const int t_s = tid >> 2;
    const int ko  = (tid & 3) * 8;
    const int wk  = tid >> 3;
    const int wmo = (tid & 7) * 8;

    float scarry = 0.0f;

    for (int c = 0; c < NC; c++) {
        float acc0[4][4], acc1[4][4], acc2[4][4];
        #pragma unroll
        for (int ii = 0; ii < 4; ii++)
            #pragma unroll
            for (int jj = 0; jj < 4; jj++) {
                acc0[ii][jj] = bl[jj]; acc1[ii][jj] = bd[jj]; acc2[ii][jj] = bi[jj];
            }

        const size_t xbase = ((size_t)b*T_ + (size_t)c*BT) * DIN;

        for (int kk0 = 0; kk0 < DIN; kk0 += 32) {
            {
                float a[8];
                ld8<BF16>(x, xbase + (size_t)t_s*DIN + kk0 + ko, a);
                #pragma unroll
                for (int q = 0; q < 8; q++)
                    xsT[(ko + q)*LDSTR + t_s] = a[q];
            }
            #pragma unroll
            for (int mat = 0; mat < 3; mat++) {
                const void* Wp = (mat == 0) ? Wlam : (mat == 1) ? Wdelt : Winp;
                float a[8];
                ld8<BF16>(Wp, (size_t)(kk0 + wk)*DM + mt*64 + wmo, a);
                float* dst = &w3[(mat*32 + wk)*LDSTR + wmo];
                *(float4*)(dst)     = make_float4(a[0],a[1],a[2],a[3]);
                *(float4*)(dst + 4) = make_float4(a[4],a[5],a[6],a[7]);
            }
            __syncthreads();

            #pragma unroll 8
            for (int kkk = 0; kkk < 32; kkk++) {
                float4 xa = *(const float4*)&xsT[kkk*LDSTR + ty*4];
                float4 w0 = *(const float4*)&w3[( 0 + kkk)*LDSTR + tx*4];
                float4 w1 = *(const float4*)&w3[(32 + kkk)*LDSTR + tx*4];
                float4 w2 = *(const float4*)&w3[(64 + kkk)*LDSTR + tx*4];
                float xv[4]  = {xa.x, xa.y, xa.z, xa.w};
                float w0v[4] = {w0.x, w0.y, w0.z, w0.w};
                float w1v[4] = {w1.x, w1.y, w1.z, w1.w};
                float w2v[4] = {w2.x, w2.y, w2.z, w2.w};
                #pragma unroll
                for (int ii = 0; ii < 4; ii++)
                    #pragma unroll
                    for (int jj = 0; jj < 4; jj++) {
                        acc0[ii][jj] = fmaf(xv[ii], w0v[jj], acc0[ii][jj]);
                        acc1[ii][jj] = fmaf(xv[ii], w1v[jj], acc1[ii][jj]);
                        acc2[ii][jj] = fmaf(xv[ii], w2v[jj], acc2[ii][jj]);
                    }
            }
            __syncthreads();
        }

        #pragma unroll
        for (int ii = 0; ii < 4; ii++) {
            int t = ty*4 + ii;
            float a[4], d[4];
            #pragma unroll
            for (int jj = 0; jj < 4; jj++) {
                float lam = softplusf(acc0[ii][jj]);
                float dl  = softplusf(acc1[ii][jj]);
                a[jj] = expf(-dl * lam);
                d[jj] = dl * acc2[ii][jj];
            }
            *(float4*)&alphaS[t*LDSTR + tx*4] = make_float4(a[0],a[1],a[2],a[3]);
            *(float4*)&driveS[t*LDSTR + tx*4] = make_float4(d[0],d[1],d[2],d[3]);
        }
        __syncthreads();

        if (tid < 64) {
            float s = scarry;
            #pragma unroll 8
            for (int t = 0; t < BT; t++)
                s = fmaf(alphaS[t*LDSTR + tid], s, driveS[t*LDSTR + tid]);
            scarry = s;
        }
        __syncthreads();
    }

    if (tid < 64) {
        float partial = scarry * ld1<BF16>(Wadd, mt*64 + tid);
        #pragma unroll
        for (int off = 32; off > 0; off >>= 1)
            partial += __shfl_down(partial, off, 64);
        if (tid == 0) {
            float* outf = (float*)out;
            atomicAdd(BF16 ? &outf[b] : &outf[64 + b], partial);
        }
    }
}

// ---------------------------------------------------------------------------
// add_pred finalize: fold accumulator + bias, write in output dtype.
// ---------------------------------------------------------------------------
template<bool BF16>
__global__ __launch_bounds__(64) void add_finalize_kernel(
    const void* x, const void* badd, void* out)
{
    if (sniff_is_bf16(x) != BF16) return;
    float bb = ld1<BF16>(badd, 0);
    if (threadIdx.x < 32) {
        float* outf = (float*)out;
        if (BF16) {
            float s = outf[threadIdx.x] + bb;
            ((u16*)out)[64 + threadIdx.x] = f2bf(s);
        } else {
            outf[64 + threadIdx.x] += bb;
        }
    }
}

// ---------------------------------------------------------------------------
// parity pipeline (workspace path): parallel column sums, then finish.
// ---------------------------------------------------------------------------
__global__ __launch_bounds__(256) void colsum_zero_kernel(float* ws) {
    ws[blockIdx.x*256 + threadIdx.x] = 0.0f;   // grid 64 -> 16384 floats
}

template<bool BF16>
__global__ __launch_bounds__(256) void parity_colsum_kernel(
    const void* __restrict__ x, float* __restrict__ ws)
{
    if (sniff_is_bf16(x) != BF16) return;
    const int b  = blockIdx.x >> 3;
    const int sl = blockIdx.x & 7;
    const int tid = threadIdx.x;
    float s0 = 0.0f, s1 = 0.0f;
    const size_t xb = (size_t)b * T_ * DIN;
    for (int t = sl*256; t < (sl+1)*256; t++) {
        float a, c2;
        ld2<BF16>(x, xb + (size_t)t*DIN + 2*tid, a, c2);
        s0 += a; s1 += c2;
    }
    atomicAdd(&ws[b*512 + 2*tid    ], s0);
    atomicAdd(&ws[b*512 + 2*tid + 1], s1);
}

template<bool BF16>
__global__ __launch_bounds__(256) void parity_finish_kernel(
    const void* __restrict__ x, const float* __restrict__ ws,
    const void* __restrict__ Wth, const void* __restrict__ bth,
    const void* __restrict__ Wpar, const void* __restrict__ bpar,
    void* __restrict__ out)
{
    if (sniff_is_bf16(x) != BF16) return;

    __shared__ float xsL[512];
    __shared__ float red[256];
    __shared__ float cosL[64], sinL[64];
    const int b = blockIdx.x;
    const int tid = threadIdx.x;

    xsL[tid]       = ws[b*512 + tid];
    xsL[256 + tid] = ws[b*512 + 256 + tid];
    __syncthreads();

    {
        const int k = tid & 63, seg = tid >> 6;
        float s = 0.0f;
        #pragma unroll 8
        for (int dd = 0; dd < 128; dd++) {
            int d = seg*128 + dd;
            s = fmaf(xsL[d], ld1<BF16>(Wth, (size_t)d*K_ + k), s);
        }
        red[tid] = s;
    }
    __syncthreads();

    if (tid < 64) {
        float s = red[tid] + red[64 + tid] + red[128 + tid] + red[192 + tid];
        float ang = 3.14159265358979323846f * (s + 2048.0f * ld1<BF16>(bth, tid));
        cosL[tid] = cosf(ang);
        sinL[tid] = sinf(ang);
    }
    __syncthreads();

    if (tid < 2) {
        const int j = tid;
        float s = ld1<BF16>(bpar, j);
        for (int k = 0; k < 64; k++) {
            s = fmaf(cosL[k], ld1<BF16>(Wpar, k*2 + j), s);
            s = fmaf(sinL[k], ld1<BF16>(Wpar, (64 + k)*2 + j), s);
        }
        if (BF16) ((u16*)out)[b*2 + j] = f2bf(s);
        else      ((float*)out)[b*2 + j] = s;
    }
}

// ---------------------------------------------------------------------------
// old single-block parity (fallback when workspace is tiny)
// ---------------------------------------------------------------------------
template<bool BF16>
__global__ __launch_bounds__(256) void parity_kernel(
    const void* __restrict__ x, const void* __restrict__ Wth, const void* __restrict__ bth,
    const void* __restrict__ Wpar, const void* __restrict__ bpar, void* __restrict__ out)
{
    if (sniff_is_bf16(x) != BF16) return;

    __shared__ float xsL[512];
    __shared__ float red[256];
    __shared__ float cosL[64], sinL[64];
    const int b = blockIdx.x;
    const int tid = threadIdx.x;

    {
        float s0 = 0.0f, s1 = 0.0f;
        const size_t xb = (size_t)b * T_ * DIN;
        for (int t = 0; t < T_; t++) {
            float a, c2;
            ld2<BF16>(x, xb + (size_t)t*DIN + 2*tid, a, c2);
            s0 += a; s1 += c2;
        }
        xsL[2*tid] = s0; xsL[2*tid + 1] = s1;
    }
    __syncthreads();

    {
        const int k = tid & 63, seg = tid >> 6;
        float s = 0.0f;
        #pragma unroll 8
        for (int dd = 0; dd < 128; dd++) {
            int d = seg*128 + dd;
            s = fmaf(xsL[d], ld1<BF16>(Wth, (size_t)d*K_ + k), s);
        }
        red[tid] = s;
    }
    __syncthreads();

    if (tid < 64) {
        float s = red[tid] + red[64 + tid] + red[128 + tid] + red[192 + tid];
        float ang = 3.14159265358979323846f * (s + 2048.0f * ld1<BF16>(bth, tid));
        cosL[tid] = cosf(ang);
        sinL[tid] = sinf(ang);
    }
    __syncthreads();

    if (tid < 2) {
        const int j = tid;
        float s = ld1<BF16>(bpar, j);
        for (int k = 0; k < 64; k++) {
            s = fmaf(cosL[k], ld1<BF16>(Wpar, k*2 + j), s);
            s = fmaf(sinL[k], ld1<BF16>(Wpar, (64 + k)*2 + j), s);
        }
        if (BF16) ((u16*)out)[b*2 + j] = f2bf(s);
        else      ((float*)out)[b*2 + j] = s;
    }
}

extern "C" void kernel_launch(void* const* d_in, const int* in_sizes, int n_in,
                              void* d_out, int out_size, void* d_ws, size_t ws_size,
                              hipStream_t stream)
{
    const void* x     = d_in[0];
    const void* Wth   = d_in[1];
    const void* bth   = d_in[2];
    const void* Wlam  = d_in[3];
    const void* blam  = d_in[4];
    const void* Wdelt = d_in[5];
    const void* bdelt = d_in[6];
    const void* Winp  = d_in[7];
    const void* binp  = d_in[8];
    const void* Wpar  = d_in[9];
    const void* bpar  = d_in[10];
    const void* Wadd  = d_in[11];
    const void* badd  = d_in[12];

    const bool ws_col  = ws_size >= (size_t)WS_COL_FLOATS * 4;
    const bool ws_w    = ws_size >= (size_t)WS_W_OFF_F * 4 + (size_t)WS_W_PLANE_U32 * 2 * 4;
    const bool ws_full = ws_size >= (size_t)WS_FULL_BYTES;
    float* ws  = (float*)d_ws;
    u32*   wsw = (u32*)((char*)d_ws + WS_WFRAG_OFF_B);
    u32*   wsx = (u32*)((char*)d_ws + WS_XFRAG_OFF_B);

    zero_accum_kernel<<<1, 64, 0, stream>>>(x, d_out);

    // bf16 path: MFMA kernel (sniff-guarded; exits fast on fp32 inputs)
    fused_ssm_mfma_bf16<<<B_*16, 256, 0, stream>>>(
        x, Wlam, blam, Wdelt, bdelt, Winp, binp, Wadd, d_out);

    // fp32 path, tiered by workspace size
    if (ws_full) {
        convert_w_frag_kernel<<<256, 256, 0, stream>>>(x, Wlam, Wdelt, Winp, wsw);
        convert_x_kernel<<<8192, 256, 0, stream>>>(x, wsx);
        fused_ssm_mfma_fp32_full<<<B_*16, 256, 0, stream>>>(
            x, blam, bdelt, binp, Wadd, wsw, wsx, d_out);
    } else if (ws_w) {
        convert_w_kernel<<<768, 256, 0, stream>>>(x, Wlam, Wdelt, Winp, ws);
        fused_ssm_mfma_fp32_ws6<<<B_*16, 256, 0, stream>>>(
            x, blam, bdelt, binp, Wadd, ws, d_out);
    } else {
        fused_ssm_kernel<false><<<B_*MT, 256, 0, stream>>>(
            x, Wlam, blam, Wdelt, bdelt, Winp, binp, Wadd, d_out);
    }

    add_finalize_kernel<true ><<<1, 64, 0, stream>>>(x, badd, d_out);
    add_finalize_kernel<false><<<1, 64, 0, stream>>>(x, badd, d_out);

    if (ws_col) {
        colsum_zero_kernel<<<64, 256, 0, stream>>>(ws);
        parity_colsum_kernel<true ><<<256, 256, 0, stream>>>(x, ws);
        parity_colsum_kernel<false><<<256, 256, 0, stream>>>(x, ws);
        parity_finish_kernel<true ><<<B_, 256, 0, stream>>>(x, ws, Wth, bth, Wpar, bpar, d_out);
        parity_finish_kernel<false><<<B_, 256, 0, stream>>>(x, ws, Wth, bth, Wpar, bpar, d_out);
    } else {
        parity_kernel<true ><<<B_, 256, 0, stream>>>(x, Wth, bth, Wpar, bpar, d_out);
        parity_kernel<false><<<B_, 256, 0, stream>>>(x, Wth, bth, Wpar, bpar, d_out);
    }
}

// Round 10
// 860.106 us; speedup vs baseline: 1.3233x; 1.3151x over previous
//
#include <hip/hip_runtime.h>
#include <hip/hip_bf16.h>

#define B_   32
#define T_   2048
#define DIN  512
#define DM   1024
#define K_   64
#define BT   64
#define NC   (T_/BT)    // 32 chunks
#define MT   (DM/64)    // 16 m-tiles
#define LDSTR 68        // padded LDS row stride (floats)

typedef unsigned short u16;
typedef unsigned int   u32;

__device__ __forceinline__ float bf2f(u16 h) {
    return __uint_as_float(((u32)h) << 16);
}
__device__ __forceinline__ void bf2x2(u32 w, float& lo, float& hi) {
    lo = __uint_as_float(w << 16);
    hi = __uint_as_float(w & 0xffff0000u);
}
__device__ __forceinline__ u16 f2bf(float f) {   // round-to-nearest-even
    u32 u = __float_as_uint(f);
    u += 0x7fffu + ((u >> 16) & 1u);
    return (u16)(u >> 16);
}
// libm version (fallback VALU kernel only — keeps that path bit-stable)
__device__ __forceinline__ float softplusf(float z) {
    return fmaxf(z, 0.0f) + log1pf(expf(-fabsf(z)));
}
// fast hardware-native versions (v_exp_f32 / v_log_f32): ~20 ops vs ~150-300
__device__ __forceinline__ float softplus_fast(float z) {
    float e = __expf(-fabsf(z));             // v_mul + v_exp_f32
    return fmaxf(z, 0.0f) + __logf(1.0f + e); // v_add + v_log_f32 + v_mul + ...
}
__device__ __forceinline__ float exp_fast(float x) {
    return __expf(x);
}

// ---- dtype-agnostic loaders -------------------------------------------------
template<bool BF16>
__device__ __forceinline__ float ld1(const void* p, size_t i) {
    if (BF16) return bf2f(((const u16*)p)[i]);
    else      return ((const float*)p)[i];
}
template<bool BF16>
__device__ __forceinline__ void ld2(const void* p, size_t i, float& a, float& b) {
    if (BF16) { u32 w = *(const u32*)((const u16*)p + i); bf2x2(w, a, b); }
    else      { float2 v = *(const float2*)((const float*)p + i); a = v.x; b = v.y; }
}
template<bool BF16>
__device__ __forceinline__ void ld8(const void* p, size_t i, float* a) {
    if (BF16) {
        uint4 v = *(const uint4*)((const u16*)p + i);
        bf2x2(v.x, a[0], a[1]); bf2x2(v.y, a[2], a[3]);
        bf2x2(v.z, a[4], a[5]); bf2x2(v.w, a[6], a[7]);
    } else {
        float4 v0 = *(const float4*)((const float*)p + i);
        float4 v1 = *(const float4*)((const float*)p + i + 4);
        a[0]=v0.x; a[1]=v0.y; a[2]=v0.z; a[3]=v0.w;
        a[4]=v1.x; a[5]=v1.y; a[6]=v1.z; a[7]=v1.w;
    }
}

// ---- device-side dtype sniff (block-uniform; needs blockDim.x >= 64) --------
__device__ __forceinline__ bool sniff_is_bf16(const void* xraw) {
    __shared__ int flag_s;
    if (threadIdx.x < 64) {
        u16 w = ((const u16*)xraw)[threadIdx.x];
        float av = fabsf(bf2f(w));
        bool plausible = (av == 0.0f) || (av >= 9.094947e-13f && av <= 64.0f);
        unsigned long long m = __ballot(plausible ? 1 : 0);
        if (threadIdx.x == 0) flag_s = (__popcll(m) >= 56) ? 1 : 0;
    }
    __syncthreads();
    return flag_s != 0;
}

// ---------------------------------------------------------------------------
// zero-init the fp32 accumulator region inside d_out.
// ---------------------------------------------------------------------------
__global__ __launch_bounds__(64) void zero_accum_kernel(const void* x, void* out) {
    bool isbf = sniff_is_bf16(x);
    float* outf = (float*)out;
    if (threadIdx.x < 32) {
        if (isbf) outf[threadIdx.x] = 0.0f;
        else      outf[64 + threadIdx.x] = 0.0f;
    }
}

// ===========================================================================
// Shared MFMA machinery (layouts HW-validated in R1/R2).
// ===========================================================================
typedef __attribute__((ext_vector_type(8)))  short bf16x8;   // 8 bf16 = 4 VGPR
typedef __attribute__((ext_vector_type(16))) float f32x16;   // 32x32 acc

#define TCH 128          // t rows per chunk
#define NCH (T_/TCH)     // 16 chunks
#define A_OFF  0
#define W_OFF  16384
#define AL_OFF 0         // alphaS: 128x64 f32 = 32KB (scan phase)
#define DR_OFF 32768     // driveS: 128x64 f32 = 32KB (scan phase)

// workspace layout (bytes):
//   [0, 64K)                 : parity column-sum accumulators (32 x 512 f32)
//   [64K, 64K+6M)            : W frags (full path) OR W planes (R2 mid path)
//   [64K+6M, 64K+6M+128M)    : X frags (full path only)
#define WS_COL_FLOATS  16384
#define WS_W_OFF_F     16384
#define WS_W_PLANE_U32 (3*256*1024)
#define WS_WFRAG_OFF_B 65536ULL
#define WS_WFRAG_BYTES (16ULL*16*24*1024)          // 6 MiB
#define WS_XFRAG_OFF_B (WS_WFRAG_OFF_B + WS_WFRAG_BYTES)
#define WS_XFRAG_BYTES (32ULL*16*16*16*1024)       // 128 MiB
#define WS_FULL_BYTES  (WS_XFRAG_OFF_B + WS_XFRAG_BYTES)

// ---------------------------------------------------------------------------
// bf16-path fused SSM on MFMA (fast activation; layouts HW-validated).
// ---------------------------------------------------------------------------
#define KC  64
__global__ __launch_bounds__(256, 2) void fused_ssm_mfma_bf16(
    const void* __restrict__ x,
    const void* __restrict__ Wlam, const void* __restrict__ blam,
    const void* __restrict__ Wdelt, const void* __restrict__ bdelt,
    const void* __restrict__ Winp, const void* __restrict__ binp,
    const void* __restrict__ Wadd,
    void* __restrict__ out)
{
    __shared__ __align__(16) unsigned char LDS[65536];

    const int tid = threadIdx.x;

    {   // inline dtype sniff (flag in LDS[0]); bf16 only proceeds
        int* flag = (int*)LDS;
        if (tid < 64) {
            u16 w0 = ((const u16*)x)[tid];
            float av = fabsf(bf2f(w0));
            bool plausible = (av == 0.0f) || (av >= 9.094947e-13f && av <= 64.0f);
            unsigned long long m = __ballot(plausible ? 1 : 0);
            if (tid == 0) *flag = (__popcll(m) >= 56) ? 1 : 0;
        }
        __syncthreads();
        int isbf = *flag;
        __syncthreads();
        if (!isbf) return;
    }

    const int swz = (blockIdx.x & 7) * 64 + (blockIdx.x >> 3);
    const int mg  = swz & 15;
    const int b   = swz >> 4;
    const int m0  = mg * 64;

    const int lane = tid & 63;
    const int w    = tid >> 6;
    const int p    = w >> 1;
    const int h    = w & 1;
    const int lr   = lane & 31;
    const int lg   = lane >> 5;

    const int colg = m0 + h*32 + lr;
    const float bL = bf2f(((const u16*)blam )[colg]);
    const float bD = bf2f(((const u16*)bdelt)[colg]);
    const float bI = bf2f(((const u16*)binp )[colg]);

    float* alphaS = (float*)(LDS + AL_OFF);
    float* driveS = (float*)(LDS + DR_OFF);

    float scarry = 0.0f;

    #pragma unroll 1
    for (int c = 0; c < NCH; c++) {
        f32x16 aL0, aL1, aD0, aD1, aI0, aI1;
        #pragma unroll
        for (int r = 0; r < 16; r++) {
            aL0[r] = bL; aL1[r] = bL;
            aD0[r] = bD; aD1[r] = bD;
            aI0[r] = bI; aI1[r] = bI;
        }

        #pragma unroll 1
        for (int kc = 0; kc < DIN/KC; kc++) {
            {
                const int t_l  = tid >> 1;
                const int half = tid & 1;
                const u16* xp = (const u16*)x
                    + ((size_t)b*T_ + (size_t)c*TCH + t_l)*DIN + kc*KC + half*32;
                uint4 v[4];
                v[0] = *(const uint4*)(xp);
                v[1] = *(const uint4*)(xp + 8);
                v[2] = *(const uint4*)(xp + 16);
                v[3] = *(const uint4*)(xp + 24);
                const int tt = t_l >> 5, tr = t_l & 31;
                #pragma unroll
                for (int q = 0; q < 4; q++) {
                    const int o  = half*4 + q;
                    const int ks = o >> 1, g = o & 1;
                    *(uint4*)(LDS + A_OFF + ((tt*4 + ks) << 10) + ((g*32 + tr) << 4)) = v[q];
                }
            }
            #pragma unroll
            for (int i = 0; i < 6; i++) {
                const int f   = w + 4*i;
                const int nt  = f >> 2, ks = f & 3;
                const int hh  = (nt >= 3) ? 1 : 0;
                const int mat = nt - 3*hh;
                const u16* Wp = (const u16*)(mat == 0 ? Wlam : (mat == 1 ? Wdelt : Winp));
                const size_t base = (size_t)(kc*KC + ks*16 + lg*8)*DM + (size_t)(m0 + hh*32 + lr);
                u32 e0 = Wp[base        ];
                u32 e1 = Wp[base +   DM ];
                u32 e2 = Wp[base + 2*DM ];
                u32 e3 = Wp[base + 3*DM ];
                u32 e4 = Wp[base + 4*DM ];
                u32 e5 = Wp[base + 5*DM ];
                u32 e6 = Wp[base + 6*DM ];
                u32 e7 = Wp[base + 7*DM ];
                uint4 pk;
                pk.x = e0 | (e1 << 16);
                pk.y = e2 | (e3 << 16);
                pk.z = e4 | (e5 << 16);
                pk.w = e6 | (e7 << 16);
                *(uint4*)(LDS + W_OFF + (f << 10) + (lane << 4)) = pk;
            }
            __syncthreads();

            #pragma unroll
            for (int ks = 0; ks < 4; ks++) {
                bf16x8 a0 = *(const bf16x8*)(LDS + A_OFF + (((2*p    )*4 + ks) << 10) + (lane << 4));
                bf16x8 a1 = *(const bf16x8*)(LDS + A_OFF + (((2*p + 1)*4 + ks) << 10) + (lane << 4));
                bf16x8 vL = *(const bf16x8*)(LDS + W_OFF + (((h*3 + 0)*4 + ks) << 10) + (lane << 4));
                bf16x8 vD = *(const bf16x8*)(LDS + W_OFF + (((h*3 + 1)*4 + ks) << 10) + (lane << 4));
                bf16x8 vI = *(const bf16x8*)(LDS + W_OFF + (((h*3 + 2)*4 + ks) << 10) + (lane << 4));
                aL0 = __builtin_amdgcn_mfma_f32_32x32x16_bf16(a0, vL, aL0, 0, 0, 0);
                aL1 = __builtin_amdgcn_mfma_f32_32x32x16_bf16(a1, vL, aL1, 0, 0, 0);
                aD0 = __builtin_amdgcn_mfma_f32_32x32x16_bf16(a0, vD, aD0, 0, 0, 0);
                aD1 = __builtin_amdgcn_mfma_f32_32x32x16_bf16(a1, vD, aD1, 0, 0, 0);
                aI0 = __builtin_amdgcn_mfma_f32_32x32x16_bf16(a0, vI, aI0, 0, 0, 0);
                aI1 = __builtin_amdgcn_mfma_f32_32x32x16_bf16(a1, vI, aI1, 0, 0, 0);
            }
            __syncthreads();
        }

        #pragma unroll
        for (int tt2 = 0; tt2 < 2; tt2++) {
            #pragma unroll
            for (int r = 0; r < 16; r++) {
                const float zl = tt2 ? aL1[r] : aL0[r];
                const float zd = tt2 ? aD1[r] : aD0[r];
                const float zi = tt2 ? aI1[r] : aI0[r];
                const float lam = softplus_fast(zl);
                const float dl  = softplus_fast(zd);
                const float av  = exp_fast(-dl * lam);
                const float dv  = dl * zi;
                const int t_loc = (2*p + tt2)*32 + (r & 3) + 8*(r >> 2) + 4*lg;
                const int m_loc = h*32 + lr;
                alphaS[t_loc*64 + m_loc] = av;
                driveS[t_loc*64 + m_loc] = dv;
            }
        }
        __syncthreads();

        if (tid < 64) {
            float s = scarry;
            #pragma unroll 8
            for (int t = 0; t < TCH; t++)
                s = fmaf(alphaS[t*64 + tid], s, driveS[t*64 + tid]);
            scarry = s;
        }
        __syncthreads();
    }

    if (tid < 64) {
        float partial = scarry * bf2f(((const u16*)Wadd)[m0 + tid]);
        #pragma unroll
        for (int off = 32; off > 0; off >>= 1)
            partial += __shfl_down(partial, off, 64);
        if (tid == 0)
            atomicAdd(&((float*)out)[b], partial);
    }
}

// ---------------------------------------------------------------------------
// R2 mid-path precursor — W planes, pair-packed (kept as fallback).
// ---------------------------------------------------------------------------
__global__ __launch_bounds__(256) void convert_w_kernel(
    const void* __restrict__ x,
    const void* __restrict__ Wlam, const void* __restrict__ Wdelt,
    const void* __restrict__ Winp, float* __restrict__ ws)
{
    if (sniff_is_bf16(x)) return;
    const int mat = blockIdx.x >> 8;
    const int kp  = blockIdx.x & 255;
    const float* Wp = (mat == 0) ? (const float*)Wlam
                    : (mat == 1) ? (const float*)Wdelt : (const float*)Winp;
    u32* whi = (u32*)(ws + WS_W_OFF_F);
    u32* wlo = whi + WS_W_PLANE_U32;
    const size_t ro = (size_t)(2*kp)*DM;
    const size_t wo = ((size_t)mat*256 + kp)*DM;
    #pragma unroll
    for (int mm = 0; mm < 4; mm++) {
        const int m = mm*256 + threadIdx.x;
        float a0 = Wp[ro + m];
        float a1 = Wp[ro + DM + m];
        u16 h0 = f2bf(a0), h1 = f2bf(a1);
        float l0 = a0 - bf2f(h0);
        float l1 = a1 - bf2f(h1);
        whi[wo + m] = (u32)h0 | ((u32)h1 << 16);
        wlo[wo + m] = (__float_as_uint(l0) >> 16) | (__float_as_uint(l1) & 0xffff0000u);
    }
}

// ---------------------------------------------------------------------------
// W -> frag-linear split-bf16: wsw[mg][kc][f(24)][1KB].
// ---------------------------------------------------------------------------
__global__ __launch_bounds__(256) void convert_w_frag_kernel(
    const void* __restrict__ x,
    const void* __restrict__ Wlam, const void* __restrict__ Wdelt,
    const void* __restrict__ Winp, u32* __restrict__ wsw)
{
    if (sniff_is_bf16(x)) return;
    const int kc = blockIdx.x & 15;
    const int mg = blockIdx.x >> 4;
    const int m0 = mg*64;
    u32* dst = wsw + (size_t)(mg*16 + kc) * 6144;   // 24*256 u32
    #pragma unroll
    for (int i = 0; i < 6; i++) {
        const int u = threadIdx.x + 256*i;   // 0..1535
        const int f = u >> 6;                // 0..23
        const int l = u & 63;
        const int hl = f & 1, ks = (f >> 1) & 1, nt = f >> 2;
        const int hh = nt / 3, mat = nt % 3;
        const float* Wp = (mat == 0) ? (const float*)Wlam
                        : (mat == 1) ? (const float*)Wdelt : (const float*)Winp;
        const int lr = l & 31, lg = l >> 5;
        const int kp0 = kc*16 + ks*8 + lg*4;
        const int m = m0 + hh*32 + lr;
        u32 q4[4];
        #pragma unroll
        for (int q = 0; q < 4; q++) {
            float a0 = Wp[(size_t)(2*(kp0+q)    )*DM + m];
            float a1 = Wp[(size_t)(2*(kp0+q) + 1)*DM + m];
            u16 h0 = f2bf(a0), h1 = f2bf(a1);
            if (hl == 0) {
                q4[q] = (u32)h0 | ((u32)h1 << 16);
            } else {
                float l0 = a0 - bf2f(h0);
                float l1 = a1 - bf2f(h1);
                q4[q] = (__float_as_uint(l0) >> 16) | (__float_as_uint(l1) & 0xffff0000u);
            }
        }
        *(uint4*)(dst + f*256 + l*4) = make_uint4(q4[0], q4[1], q4[2], q4[3]);
    }
}

// ---------------------------------------------------------------------------
// x -> frag-linear split-bf16: wsx[b][c][kc][f(16)][1KB].
// ---------------------------------------------------------------------------
#define KC2 32
__global__ __launch_bounds__(256) void convert_x_kernel(
    const void* __restrict__ x, u32* __restrict__ wsx)
{
    if (sniff_is_bf16(x)) return;
    const int kc = blockIdx.x & 15;
    const int c  = (blockIdx.x >> 4) & 15;
    const int b  = blockIdx.x >> 8;
    const int tid = threadIdx.x;
    const int t_l  = tid >> 1;          // 0..127
    const int half = tid & 1;           // = ks
    const float* xp = (const float*)x
        + ((size_t)b*T_ + (size_t)c*TCH + t_l)*DIN + kc*KC2 + half*16;
    float vv[16];
    *(float4*)(vv)      = *(const float4*)(xp);
    *(float4*)(vv + 4)  = *(const float4*)(xp + 4);
    *(float4*)(vv + 8)  = *(const float4*)(xp + 8);
    *(float4*)(vv + 12) = *(const float4*)(xp + 12);
    u32 hi[8], lo[8];
    #pragma unroll
    for (int q = 0; q < 8; q++) {
        const float a0 = vv[2*q], a1 = vv[2*q+1];
        const u16 h0 = f2bf(a0), h1 = f2bf(a1);
        hi[q] = (u32)h0 | ((u32)h1 << 16);
        const float l0 = a0 - bf2f(h0);
        const float l1 = a1 - bf2f(h1);
        lo[q] = (__float_as_uint(l0) >> 16) | (__float_as_uint(l1) & 0xffff0000u);
    }
    u32* dst = wsx + ((((size_t)b*16 + c)*16 + kc) << 12);   // *4096 u32
    const int tt = t_l >> 5, tr = t_l & 31;
    const int fb = (tt*2 + half)*2;
    *(uint4*)(dst + fb*256     + (0*32 + tr)*4) = make_uint4(hi[0],hi[1],hi[2],hi[3]);
    *(uint4*)(dst + fb*256     + (1*32 + tr)*4) = make_uint4(hi[4],hi[5],hi[6],hi[7]);
    *(uint4*)(dst + (fb+1)*256 + (0*32 + tr)*4) = make_uint4(lo[0],lo[1],lo[2],lo[3]);
    *(uint4*)(dst + (fb+1)*256 + (1*32 + tr)*4) = make_uint4(lo[4],lo[5],lo[6],lo[7]);
}

// ---------------------------------------------------------------------------
// fp32-path fused SSM, full-workspace (R10: revert to R7 structure — the
// measured-best 839 µs reg-staged dbuf with issue-early/write-late — plus
// fast hardware-native activation (v_exp_f32/v_log_f32 via __expf/__logf)
// replacing libm softplus/exp. Everything else byte-identical to R7.
// ---------------------------------------------------------------------------
#define STG_B 40960   // one staging buffer: A 16KB @ +0, W 24KB @ +16384
__global__ __launch_bounds__(256, 2) void fused_ssm_mfma_fp32_full(
    const void* __restrict__ x,
    const void* __restrict__ blam, const void* __restrict__ bdelt,
    const void* __restrict__ binp, const void* __restrict__ Wadd,
    const u32* __restrict__ wsw, const u32* __restrict__ wsx,
    void* __restrict__ out)
{
    __shared__ __align__(16) unsigned char LDS[2*STG_B];   // 80 KB

    const int tid = threadIdx.x;

    {   // inline dtype sniff; fp32 only proceeds
        int* flag = (int*)LDS;
        if (tid < 64) {
            u16 w0 = ((const u16*)x)[tid];
            float av = fabsf(bf2f(w0));
            bool plausible = (av == 0.0f) || (av >= 9.094947e-13f && av <= 64.0f);
            unsigned long long m = __ballot(plausible ? 1 : 0);
            if (tid == 0) *flag = (__popcll(m) >= 56) ? 1 : 0;
        }
        __syncthreads();
        int isbf = *flag;
        __syncthreads();
        if (isbf) return;
    }

    const int swz = (blockIdx.x & 7) * 64 + (blockIdx.x >> 3);
    const int mg  = swz & 15;
    const int b   = swz >> 4;
    const int m0  = mg * 64;

    const int lane = tid & 63;
    const int w    = tid >> 6;
    const int p    = w >> 1;
    const int h    = w & 1;
    const int lr   = lane & 31;
    const int lg   = lane >> 5;

    const int colg = m0 + h*32 + lr;
    const float bL = ((const float*)blam )[colg];
    const float bD = ((const float*)bdelt)[colg];
    const float bI = ((const float*)binp )[colg];

    float* alphaS = (float*)(LDS + AL_OFF);
    float* driveS = (float*)(LDS + DR_OFF);

    float scarry = 0.0f;

    #pragma unroll 1
    for (int c = 0; c < NCH; c++) {
        f32x16 aL0, aL1, aD0, aD1, aI0, aI1;
        #pragma unroll
        for (int r = 0; r < 16; r++) {
            aL0[r] = bL; aL1[r] = bL;
            aD0[r] = bD; aD1[r] = bD;
            aI0[r] = bI; aI1[r] = bI;
        }

        // per-thread global bases for this chunk (u32 units)
        const u32* gaB = wsx + ((((size_t)b*16 + c)*16) << 12) + (size_t)tid*4;
        const u32* gwB = wsw + (size_t)(mg*16)*6144 + (size_t)tid*4;

        // ---- chunk prologue: stage kc=0 into buf0 (one full stall/chunk) ----
        {
            uint4 a0 = *(const uint4*)(gaB);
            uint4 a1 = *(const uint4*)(gaB + 1024);
            uint4 a2 = *(const uint4*)(gaB + 2048);
            uint4 a3 = *(const uint4*)(gaB + 3072);
            uint4 w0 = *(const uint4*)(gwB);
            uint4 w1 = *(const uint4*)(gwB + 1024);
            uint4 w2 = *(const uint4*)(gwB + 2048);
            uint4 w3 = *(const uint4*)(gwB + 3072);
            uint4 w4 = *(const uint4*)(gwB + 4096);
            uint4 w5 = *(const uint4*)(gwB + 5120);
            *(uint4*)(LDS + (tid << 4))                 = a0;
            *(uint4*)(LDS + (tid << 4) + 4096)          = a1;
            *(uint4*)(LDS + (tid << 4) + 8192)          = a2;
            *(uint4*)(LDS + (tid << 4) + 12288)         = a3;
            *(uint4*)(LDS + 16384 + (tid << 4))         = w0;
            *(uint4*)(LDS + 16384 + (tid << 4) + 4096)  = w1;
            *(uint4*)(LDS + 16384 + (tid << 4) + 8192)  = w2;
            *(uint4*)(LDS + 16384 + (tid << 4) + 12288) = w3;
            *(uint4*)(LDS + 16384 + (tid << 4) + 16384) = w4;
            *(uint4*)(LDS + 16384 + (tid << 4) + 20480) = w5;
        }
        __syncthreads();

        #pragma unroll 1
        for (int kc = 0; kc < DIN/KC2; kc++) {
            unsigned char* cur = LDS + (kc & 1)*STG_B;
            unsigned char* nxt = LDS + ((kc + 1) & 1)*STG_B;
            const bool pf = (kc < DIN/KC2 - 1);

            // ---- 1. issue next-kc loads (named scalars; drain under MFMAs)
            uint4 a0, a1, a2, a3, w0, w1, w2, w3, w4, w5;
            if (pf) {
                const u32* ga = gaB + (size_t)(kc + 1)*4096;
                const u32* gw = gwB + (size_t)(kc + 1)*6144;
                a0 = *(const uint4*)(ga);
                a1 = *(const uint4*)(ga + 1024);
                a2 = *(const uint4*)(ga + 2048);
                a3 = *(const uint4*)(ga + 3072);
                w0 = *(const uint4*)(gw);
                w1 = *(const uint4*)(gw + 1024);
                w2 = *(const uint4*)(gw + 2048);
                w3 = *(const uint4*)(gw + 3072);
                w4 = *(const uint4*)(gw + 4096);
                w5 = *(const uint4*)(gw + 5120);
            }

            // ---- 2. MFMA on current buffer: 2 K-steps x (2 tt x 3 mats x 3)
            #pragma unroll
            for (int ks = 0; ks < 2; ks++) {
                const int fa0 = ((2*p    )*2 + ks)*2;
                const int fa1 = ((2*p + 1)*2 + ks)*2;
                const int fL  = ((h*3 + 0)*2 + ks)*2;
                const int fD  = ((h*3 + 1)*2 + ks)*2;
                const int fI  = ((h*3 + 2)*2 + ks)*2;
                bf16x8 a0h = *(const bf16x8*)(cur + (fa0     << 10) + (lane << 4));
                bf16x8 a0l = *(const bf16x8*)(cur + ((fa0+1) << 10) + (lane << 4));
                bf16x8 a1h = *(const bf16x8*)(cur + (fa1     << 10) + (lane << 4));
                bf16x8 a1l = *(const bf16x8*)(cur + ((fa1+1) << 10) + (lane << 4));
                bf16x8 vLh = *(const bf16x8*)(cur + 16384 + (fL      << 10) + (lane << 4));
                bf16x8 vLl = *(const bf16x8*)(cur + 16384 + ((fL+1)  << 10) + (lane << 4));
                bf16x8 vDh = *(const bf16x8*)(cur + 16384 + (fD      << 10) + (lane << 4));
                bf16x8 vDl = *(const bf16x8*)(cur + 16384 + ((fD+1)  << 10) + (lane << 4));
                bf16x8 vIh = *(const bf16x8*)(cur + 16384 + (fI      << 10) + (lane << 4));
                bf16x8 vIl = *(const bf16x8*)(cur + 16384 + ((fI+1)  << 10) + (lane << 4));
                aL0 = __builtin_amdgcn_mfma_f32_32x32x16_bf16(a0h, vLh, aL0, 0, 0, 0);
                aL0 = __builtin_amdgcn_mfma_f32_32x32x16_bf16(a0h, vLl, aL0, 0, 0, 0);
                aL0 = __builtin_amdgcn_mfma_f32_32x32x16_bf16(a0l, vLh, aL0, 0, 0, 0);
                aL1 = __builtin_amdgcn_mfma_f32_32x32x16_bf16(a1h, vLh, aL1, 0, 0, 0);
                aL1 = __builtin_amdgcn_mfma_f32_32x32x16_bf16(a1h, vLl, aL1, 0, 0, 0);
                aL1 = __builtin_amdgcn_mfma_f32_32x32x16_bf16(a1l, vLh, aL1, 0, 0, 0);
                aD0 = __builtin_amdgcn_mfma_f32_32x32x16_bf16(a0h, vDh, aD0, 0, 0, 0);
                aD0 = __builtin_amdgcn_mfma_f32_32x32x16_bf16(a0h, vDl, aD0, 0, 0, 0);
                aD0 = __builtin_amdgcn_mfma_f32_32x32x16_bf16(a0l, vDh, aD0, 0, 0, 0);
                aD1 = __builtin_amdgcn_mfma_f32_32x32x16_bf16(a1h, vDh, aD1, 0, 0, 0);
                aD1 = __builtin_amdgcn_mfma_f32_32x32x16_bf16(a1h, vDl, aD1, 0, 0, 0);
                aD1 = __builtin_amdgcn_mfma_f32_32x32x16_bf16(a1l, vDh, aD1, 0, 0, 0);
                aI0 = __builtin_amdgcn_mfma_f32_32x32x16_bf16(a0h, vIh, aI0, 0, 0, 0);
                aI0 = __builtin_amdgcn_mfma_f32_32x32x16_bf16(a0h, vIl, aI0, 0, 0, 0);
                aI0 = __builtin_amdgcn_mfma_f32_32x32x16_bf16(a0l, vIh, aI0, 0, 0, 0);
                aI1 = __builtin_amdgcn_mfma_f32_32x32x16_bf16(a1h, vIh, aI1, 0, 0, 0);
                aI1 = __builtin_amdgcn_mfma_f32_32x32x16_bf16(a1h, vIl, aI1, 0, 0, 0);
                aI1 = __builtin_amdgcn_mfma_f32_32x32x16_bf16(a1l, vIh, aI1, 0, 0, 0);
            }

            // ---- 3. write next-kc frags into the other buffer (vmcnt here,
            //         after the MFMA cluster — near-zero residual wait)
            if (pf) {
                *(uint4*)(nxt + (tid << 4))                 = a0;
                *(uint4*)(nxt + (tid << 4) + 4096)          = a1;
                *(uint4*)(nxt + (tid << 4) + 8192)          = a2;
                *(uint4*)(nxt + (tid << 4) + 12288)         = a3;
                *(uint4*)(nxt + 16384 + (tid << 4))         = w0;
                *(uint4*)(nxt + 16384 + (tid << 4) + 4096)  = w1;
                *(uint4*)(nxt + 16384 + (tid << 4) + 8192)  = w2;
                *(uint4*)(nxt + 16384 + (tid << 4) + 12288) = w3;
                *(uint4*)(nxt + 16384 + (tid << 4) + 16384) = w4;
                *(uint4*)(nxt + 16384 + (tid << 4) + 20480) = w5;
            }
            __syncthreads();   // nxt fully written + cur fully read
        }

        // ---- activation (fast hardware transcendentals) ----
        #pragma unroll
        for (int tt2 = 0; tt2 < 2; tt2++) {
            #pragma unroll
            for (int r = 0; r < 16; r++) {
                const float zl = tt2 ? aL1[r] : aL0[r];
                const float zd = tt2 ? aD1[r] : aD0[r];
                const float zi = tt2 ? aI1[r] : aI0[r];
                const float lam = softplus_fast(zl);
                const float dl  = softplus_fast(zd);
                const float av  = exp_fast(-dl * lam);
                const float dv  = dl * zi;
                const int t_loc = (2*p + tt2)*32 + (r & 3) + 8*(r >> 2) + 4*lg;
                const int m_loc = h*32 + lr;
                alphaS[t_loc*64 + m_loc] = av;
                driveS[t_loc*64 + m_loc] = dv;
            }
        }
        __syncthreads();

        // ---- in-chunk scan, one thread per m column ----
        if (tid < 64) {
            float s = scarry;
            #pragma unroll 8
            for (int t = 0; t < TCH; t++)
                s = fmaf(alphaS[t*64 + tid], s, driveS[t*64 + tid]);
            scarry = s;
        }
        __syncthreads();
    }

    if (tid < 64) {
        float partial = scarry * ((const float*)Wadd)[m0 + tid];
        #pragma unroll
        for (int off = 32; off > 0; off >>= 1)
            partial += __shfl_down(partial, off, 64);
        if (tid == 0)
            atomicAdd(&((float*)out)[64 + b], partial);
    }
}

// ---------------------------------------------------------------------------
// R2 fp32-path fused SSM (mid-workspace fallback) — fast activation applied.
// ---------------------------------------------------------------------------
__global__ __launch_bounds__(256, 2) void fused_ssm_mfma_fp32_ws6(
    const void* __restrict__ x,
    const void* __restrict__ blam, const void* __restrict__ bdelt,
    const void* __restrict__ binp, const void* __restrict__ Wadd,
    const float* __restrict__ ws,
    void* __restrict__ out)
{
    __shared__ __align__(16) unsigned char LDS[65536];

    const int tid = threadIdx.x;

    {
        int* flag = (int*)LDS;
        if (tid < 64) {
            u16 w0 = ((const u16*)x)[tid];
            float av = fabsf(bf2f(w0));
            bool plausible = (av == 0.0f) || (av >= 9.094947e-13f && av <= 64.0f);
            unsigned long long m = __ballot(plausible ? 1 : 0);
            if (tid == 0) *flag = (__popcll(m) >= 56) ? 1 : 0;
        }
        __syncthreads();
        int isbf = *flag;
        __syncthreads();
        if (isbf) return;
    }

    const u32* whi = (const u32*)(ws + WS_W_OFF_F);
    const u32* wlo = whi + WS_W_PLANE_U32;

    const int swz = (blockIdx.x & 7) * 64 + (blockIdx.x >> 3);
    const int mg  = swz & 15;
    const int b   = swz >> 4;
    const int m0  = mg * 64;

    const int lane = tid & 63;
    const int w    = tid >> 6;
    const int p    = w >> 1;
    const int h    = w & 1;
    const int lr   = lane & 31;
    const int lg   = lane >> 5;

    const int colg = m0 + h*32 + lr;
    const float bL = ((const float*)blam )[colg];
    const float bD = ((const float*)bdelt)[colg];
    const float bI = ((const float*)binp )[colg];

    int fhi_[3], kp0_[3]; size_t wb_[3];
    #pragma unroll
    for (int i = 0; i < 3; i++) {
        const int u2 = w + 4*i;
        const int ks = u2 & 1, mu = u2 >> 1;
        const int mat = mu % 3, hh = mu / 3;
        fhi_[i] = 2*u2;
        kp0_[i] = ks*8 + lg*4;
        wb_[i]  = ((size_t)mat*256)*DM + (size_t)(m0 + hh*32 + lr);
    }

    float* alphaS = (float*)(LDS + AL_OFF);
    float* driveS = (float*)(LDS + DR_OFF);

    float scarry = 0.0f;

    #pragma unroll 1
    for (int c = 0; c < NCH; c++) {
        f32x16 aL0, aL1, aD0, aD1, aI0, aI1;
        #pragma unroll
        for (int r = 0; r < 16; r++) {
            aL0[r] = bL; aL1[r] = bL;
            aD0[r] = bD; aD1[r] = bD;
            aI0[r] = bI; aI1[r] = bI;
        }

        #pragma unroll 1
        for (int kc = 0; kc < DIN/KC2; kc++) {
            {
                const int t_l  = tid >> 1;
                const int half = tid & 1;
                const float* xp = (const float*)x
                    + ((size_t)b*T_ + (size_t)c*TCH + t_l)*DIN + kc*KC2 + half*16;
                float vv[16];
                *(float4*)(vv)      = *(const float4*)(xp);
                *(float4*)(vv + 4)  = *(const float4*)(xp + 4);
                *(float4*)(vv + 8)  = *(const float4*)(xp + 8);
                *(float4*)(vv + 12) = *(const float4*)(xp + 12);
                u32 hi[8], lo[8];
                #pragma unroll
                for (int q = 0; q < 8; q++) {
                    const float a0 = vv[2*q], a1 = vv[2*q+1];
                    const u16 h0 = f2bf(a0), h1 = f2bf(a1);
                    hi[q] = (u32)h0 | ((u32)h1 << 16);
                    const float l0 = a0 - bf2f(h0);
                    const float l1 = a1 - bf2f(h1);
                    lo[q] = (__float_as_uint(l0) >> 16) | (__float_as_uint(l1) & 0xffff0000u);
                }
                const int tt = t_l >> 5, tr = t_l & 31;
                const int fb = (tt*2 + half)*2;
                *(uint4*)(LDS + A_OFF + (fb << 10)     + ((0*32 + tr) << 4)) = make_uint4(hi[0],hi[1],hi[2],hi[3]);
                *(uint4*)(LDS + A_OFF + (fb << 10)     + ((1*32 + tr) << 4)) = make_uint4(hi[4],hi[5],hi[6],hi[7]);
                *(uint4*)(LDS + A_OFF + ((fb+1) << 10) + ((0*32 + tr) << 4)) = make_uint4(lo[0],lo[1],lo[2],lo[3]);
                *(uint4*)(LDS + A_OFF + ((fb+1) << 10) + ((1*32 + tr) << 4)) = make_uint4(lo[4],lo[5],lo[6],lo[7]);
            }
            #pragma unroll
            for (int i = 0; i < 3; i++) {
                const size_t base = wb_[i] + (size_t)(kc*16 + kp0_[i])*DM;
                uint4 ph, pl;
                ph.x = whi[base]; ph.y = whi[base + DM]; ph.z = whi[base + 2*DM]; ph.w = whi[base + 3*DM];
                pl.x = wlo[base]; pl.y = wlo[base + DM]; pl.z = wlo[base + 2*DM]; pl.w = wlo[base + 3*DM];
                *(uint4*)(LDS + W_OFF + (fhi_[i] << 10)       + (lane << 4)) = ph;
                *(uint4*)(LDS + W_OFF + ((fhi_[i] + 1) << 10) + (lane << 4)) = pl;
            }
            __syncthreads();

            #pragma unroll
            for (int ks = 0; ks < 2; ks++) {
                const int fa0 = ((2*p    )*2 + ks)*2;
                const int fa1 = ((2*p + 1)*2 + ks)*2;
                const int fL  = ((h*3 + 0)*2 + ks)*2;
                const int fD  = ((h*3 + 1)*2 + ks)*2;
                const int fI  = ((h*3 + 2)*2 + ks)*2;
                bf16x8 a0h = *(const bf16x8*)(LDS + A_OFF + (fa0     << 10) + (lane << 4));
                bf16x8 a0l = *(const bf16x8*)(LDS + A_OFF + ((fa0+1) << 10) + (lane << 4));
                bf16x8 a1h = *(const bf16x8*)(LDS + A_OFF + (fa1     << 10) + (lane << 4));
                bf16x8 a1l = *(const bf16x8*)(LDS + A_OFF + ((fa1+1) << 10) + (lane << 4));
                bf16x8 vLh = *(const bf16x8*)(LDS + W_OFF + (fL      << 10) + (lane << 4));
                bf16x8 vLl = *(const bf16x8*)(LDS + W_OFF + ((fL+1)  << 10) + (lane << 4));
                bf16x8 vDh = *(const bf16x8*)(LDS + W_OFF + (fD      << 10) + (lane << 4));
                bf16x8 vDl = *(const bf16x8*)(LDS + W_OFF + ((fD+1)  << 10) + (lane << 4));
                bf16x8 vIh = *(const bf16x8*)(LDS + W_OFF + (fI      << 10) + (lane << 4));
                bf16x8 vIl = *(const bf16x8*)(LDS + W_OFF + ((fI+1)  << 10) + (lane << 4));
                aL0 = __builtin_amdgcn_mfma_f32_32x32x16_bf16(a0h, vLh, aL0, 0, 0, 0);
                aL0 = __builtin_amdgcn_mfma_f32_32x32x16_bf16(a0h, vLl, aL0, 0, 0, 0);
                aL0 = __builtin_amdgcn_mfma_f32_32x32x16_bf16(a0l, vLh, aL0, 0, 0, 0);
                aL1 = __builtin_amdgcn_mfma_f32_32x32x16_bf16(a1h, vLh, aL1, 0, 0, 0);
                aL1 = __builtin_amdgcn_mfma_f32_32x32x16_bf16(a1h, vLl, aL1, 0, 0, 0);
                aL1 = __builtin_amdgcn_mfma_f32_32x32x16_bf16(a1l, vLh, aL1, 0, 0, 0);
                aD0 = __builtin_amdgcn_mfma_f32_32x32x16_bf16(a0h, vDh, aD0, 0, 0, 0);
                aD0 = __builtin_amdgcn_mfma_f32_32x32x16_bf16(a0h, vDl, aD0, 0, 0, 0);
                aD0 = __builtin_amdgcn_mfma_f32_32x32x16_bf16(a0l, vDh, aD0, 0, 0, 0);
                aD1 = __builtin_amdgcn_mfma_f32_32x32x16_bf16(a1h, vDh, aD1, 0, 0, 0);
                aD1 = __builtin_amdgcn_mfma_f32_32x32x16_bf16(a1h, vDl, aD1, 0, 0, 0);
                aD1 = __builtin_amdgcn_mfma_f32_32x32x16_bf16(a1l, vDh, aD1, 0, 0, 0);
                aI0 = __builtin_amdgcn_mfma_f32_32x32x16_bf16(a0h, vIh, aI0, 0, 0, 0);
                aI0 = __builtin_amdgcn_mfma_f32_32x32x16_bf16(a0h, vIl, aI0, 0, 0, 0);
                aI0 = __builtin_amdgcn_mfma_f32_32x32x16_bf16(a0l, vIh, aI0, 0, 0, 0);
                aI1 = __builtin_amdgcn_mfma_f32_32x32x16_bf16(a1h, vIh, aI1, 0, 0, 0);
                aI1 = __builtin_amdgcn_mfma_f32_32x32x16_bf16(a1h, vIl, aI1, 0, 0, 0);
                aI1 = __builtin_amdgcn_mfma_f32_32x32x16_bf16(a1l, vIh, aI1, 0, 0, 0);
            }
            __syncthreads();
        }

        #pragma unroll
        for (int tt2 = 0; tt2 < 2; tt2++) {
            #pragma unroll
            for (int r = 0; r < 16; r++) {
                const float zl = tt2 ? aL1[r] : aL0[r];
                const float zd = tt2 ? aD1[r] : aD0[r];
                const float zi = tt2 ? aI1[r] : aI0[r];
                const float lam = softplus_fast(zl);
                const float dl  = softplus_fast(zd);
                const float av  = exp_fast(-dl * lam);
                const float dv  = dl * zi;
                const int t_loc = (2*p + tt2)*32 + (r & 3) + 8*(r >> 2) + 4*lg;
                const int m_loc = h*32 + lr;
                alphaS[t_loc*64 + m_loc] = av;
                driveS[t_loc*64 + m_loc] = dv;
            }
        }
        __syncthreads();

        if (tid < 64) {
            float s = scarry;
            #pragma unroll 8
            for (int t = 0; t < TCH; t++)
                s = fmaf(alphaS[t*64 + tid], s, driveS[t*64 + tid]);
            scarry = s;
        }
        __syncthreads();
    }

    if (tid < 64) {
        float partial = scarry * ((const float*)Wadd)[m0 + tid];
        #pragma unroll
        for (int off = 32; off > 0; off >>= 1)
            partial += __shfl_down(partial, off, 64);
        if (tid == 0)
            atomicAdd(&((float*)out)[64 + b], partial);
    }
}

// ---------------------------------------------------------------------------
// fp32-path fused SSM on VALU — last-resort fallback (no workspace; libm).
// ---------------------------------------------------------------------------
template<bool BF16>
__global__ __launch_bounds__(256) void fused_ssm_kernel(
    const void* __restrict__ x,
    const void* __restrict__ Wlam, const void* __restrict__ blam,
    const void* __restrict__ Wdelt, const void* __restrict__ bdelt,
    const void* __restrict__ Winp, const void* __restrict__ binp,
    const void* __restrict__ Wadd,
    void* __restrict__ out)
{
    if (sniff_is_bf16(x) != BF16) return;

    __shared__ __align__(16) float smem[8704];

    const int mt  = blockIdx.x & 15;
    const int b   = blockIdx.x >> 4;
    const int tid = threadIdx.x;
    const int tx  = tid & 15;
    const int ty  = tid >> 4;

    float bl[4], bd[4], bi[4];
    #pragma unroll
    for (int jj = 0; jj < 4; jj++) {
        int m = mt*64 + tx*4 + jj;
        bl[jj] = ld1<BF16>(blam, m); bd[jj] = ld1<BF16>(bdelt, m); bi[jj] = ld1<BF16>(binp, m);
    }

    float* xsT = smem;
    float* w3  = smem + 32*LDSTR;
    float* alphaS = smem;
    float* driveS = smem + 64*LDSTR;

    const int t_s = tid >> 2;
    const int ko  = (tid & 3) * 8;
    const int wk  = tid >> 3;
    const int wmo = (tid & 7) * 8;

    float scarry = 0.0f;

    for (int c = 0; c < NC; c++) {
        float acc0[4][4], acc1[4][4], acc2[4][4];
        #pragma unroll
        for (int ii = 0; ii < 4; ii++)
            #pragma unroll
            for (int jj = 0; jj < 4; jj++) {
                acc0[ii][jj] = bl[jj]; acc1[ii][jj] = bd[jj]; acc2[ii][jj] = bi[jj];
            }

        const size_t xbase = ((size_t)b*T_ + (size_t)c*BT) * DIN;

        for (int kk0 = 0; kk0 < DIN; kk0 += 32) {
            {
                float a[8];
                ld8<BF16>(x, xbase + (size_t)t_s*DIN + kk0 + ko, a);
                #pragma unroll
                for (int q = 0; q < 8; q++)
                    xsT[(ko + q)*LDSTR + t_s] = a[q];
            }
            #pragma unroll
            for (int mat = 0; mat < 3; mat++) {
                const void* Wp = (mat == 0) ? Wlam : (mat == 1) ? Wdelt : Winp;
                float a[8];
                ld8<BF16>(Wp, (size_t)(kk0 + wk)*DM + mt*64 + wmo, a);
                float* dst = &w3[(mat*32 + wk)*LDSTR + wmo];
                *(float4*)(dst)     = make_float4(a[0],a[1],a[2],a[3]);
                *(float4*)(dst + 4) = make_float4(a[4],a[5],a[6],a[7]);
            }
            __syncthreads();

            #pragma unroll 8
            for (int kkk = 0; kkk < 32; kkk++) {
                float4 xa = *(const float4*)&xsT[kkk*LDSTR + ty*4];
                float4 w0 = *(const float4*)&w3[( 0 + kkk)*LDSTR + tx*4];
                float4 w1 = *(const float4*)&w3[(32 + kkk)*LDSTR + tx*4];
                float4 w2 = *(const float4*)&w3[(64 + kkk)*LDSTR + tx*4];
                float xv[4]  = {xa.x, xa.y, xa.z, xa.w};
                float w0v[4] = {w0.x, w0.y, w0.z, w0.w};
                float w1v[4] = {w1.x, w1.y, w1.z, w1.w};
                float w2v[4] = {w2.x, w2.y, w2.z, w2.w};
                #pragma unroll
                for (int ii = 0; ii < 4; ii++)
                    #pragma unroll
                    for (int jj = 0; jj < 4; jj++) {
                        acc0[ii][jj] = fmaf(xv[ii], w0v[jj], acc0[ii][jj]);
                        acc1[ii][jj] = fmaf(xv[ii], w1v[jj], acc1[ii][jj]);
                        acc2[ii][jj] = fmaf(xv[ii], w2v[jj], acc2[ii][jj]);
                    }
            }
            __syncthreads();
        }

        #pragma unroll
        for (int ii = 0; ii < 4; ii++) {
            int t = ty*4 + ii;
            float a[4], d[4];
            #pragma unroll
            for (int jj = 0; jj < 4; jj++) {
                float lam = softplusf(acc0[ii][jj]);
                float dl  = softplusf(acc1[ii][jj]);
                a[jj] = expf(-dl * lam);
                d[jj] = dl * acc2[ii][jj];
            }
            *(float4*)&alphaS[t*LDSTR + tx*4] = make_float4(a[0],a[1],a[2],a[3]);
            *(float4*)&driveS[t*LDSTR + tx*4] = make_float4(d[0],d[1],d[2],d[3]);
        }
        __syncthreads();

        if (tid < 64) {
            float s = scarry;
            #pragma unroll 8
            for (int t = 0; t < BT; t++)
                s = fmaf(alphaS[t*LDSTR + tid], s, driveS[t*LDSTR + tid]);
            scarry = s;
        }
        __syncthreads();
    }

    if (tid < 64) {
        float partial = scarry * ld1<BF16>(Wadd, mt*64 + tid);
        #pragma unroll
        for (int off = 32; off > 0; off >>= 1)
            partial += __shfl_down(partial, off, 64);
        if (tid == 0) {
            float* outf = (float*)out;
            atomicAdd(BF16 ? &outf[b] : &outf[64 + b], partial);
        }
    }
}

// ---------------------------------------------------------------------------
// add_pred finalize: fold accumulator + bias, write in output dtype.
// ---------------------------------------------------------------------------
template<bool BF16>
__global__ __launch_bounds__(64) void add_finalize_kernel(
    const void* x, const void* badd, void* out)
{
    if (sniff_is_bf16(x) != BF16) return;
    float bb = ld1<BF16>(badd, 0);
    if (threadIdx.x < 32) {
        float* outf = (float*)out;
        if (BF16) {
            float s = outf[threadIdx.x] + bb;
            ((u16*)out)[64 + threadIdx.x] = f2bf(s);
        } else {
            outf[64 + threadIdx.x] += bb;
        }
    }
}

// ---------------------------------------------------------------------------
// parity pipeline (workspace path): parallel column sums, then finish.
// ---------------------------------------------------------------------------
__global__ __launch_bounds__(256) void colsum_zero_kernel(float* ws) {
    ws[blockIdx.x*256 + threadIdx.x] = 0.0f;   // grid 64 -> 16384 floats
}

template<bool BF16>
__global__ __launch_bounds__(256) void parity_colsum_kernel(
    const void* __restrict__ x, float* __restrict__ ws)
{
    if (sniff_is_bf16(x) != BF16) return;
    const int b  = blockIdx.x >> 3;
    const int sl = blockIdx.x & 7;
    const int tid = threadIdx.x;
    float s0 = 0.0f, s1 = 0.0f;
    const size_t xb = (size_t)b * T_ * DIN;
    for (int t = sl*256; t < (sl+1)*256; t++) {
        float a, c2;
        ld2<BF16>(x, xb + (size_t)t*DIN + 2*tid, a, c2);
        s0 += a; s1 += c2;
    }
    atomicAdd(&ws[b*512 + 2*tid    ], s0);
    atomicAdd(&ws[b*512 + 2*tid + 1], s1);
}

template<bool BF16>
__global__ __launch_bounds__(256) void parity_finish_kernel(
    const void* __restrict__ x, const float* __restrict__ ws,
    const void* __restrict__ Wth, const void* __restrict__ bth,
    const void* __restrict__ Wpar, const void* __restrict__ bpar,
    void* __restrict__ out)
{
    if (sniff_is_bf16(x) != BF16) return;

    __shared__ float xsL[512];
    __shared__ float red[256];
    __shared__ float cosL[64], sinL[64];
    const int b = blockIdx.x;
    const int tid = threadIdx.x;

    xsL[tid]       = ws[b*512 + tid];
    xsL[256 + tid] = ws[b*512 + 256 + tid];
    __syncthreads();

    {
        const int k = tid & 63, seg = tid >> 6;
        float s = 0.0f;
        #pragma unroll 8
        for (int dd = 0; dd < 128; dd++) {
            int d = seg*128 + dd;
            s = fmaf(xsL[d], ld1<BF16>(Wth, (size_t)d*K_ + k), s);
        }
        red[tid] = s;
    }
    __syncthreads();

    if (tid < 64) {
        float s = red[tid] + red[64 + tid] + red[128 + tid] + red[192 + tid];
        float ang = 3.14159265358979323846f * (s + 2048.0f * ld1<BF16>(bth, tid));
        cosL[tid] = cosf(ang);
        sinL[tid] = sinf(ang);
    }
    __syncthreads();

    if (tid < 2) {
        const int j = tid;
        float s = ld1<BF16>(bpar, j);
        for (int k = 0; k < 64; k++) {
            s = fmaf(cosL[k], ld1<BF16>(Wpar, k*2 + j), s);
            s = fmaf(sinL[k], ld1<BF16>(Wpar, (64 + k)*2 + j), s);
        }
        if (BF16) ((u16*)out)[b*2 + j] = f2bf(s);
        else      ((float*)out)[b*2 + j] = s;
    }
}

// ---------------------------------------------------------------------------
// old single-block parity (fallback when workspace is tiny)
// ---------------------------------------------------------------------------
template<bool BF16>
__global__ __launch_bounds__(256) void parity_kernel(
    const void* __restrict__ x, const void* __restrict__ Wth, const void* __restrict__ bth,
    const void* __restrict__ Wpar, const void* __restrict__ bpar, void* __restrict__ out)
{
    if (sniff_is_bf16(x) != BF16) return;

    __shared__ float xsL[512];
    __shared__ float red[256];
    __shared__ float cosL[64], sinL[64];
    const int b = blockIdx.x;
    const int tid = threadIdx.x;

    {
        float s0 = 0.0f, s1 = 0.0f;
        const size_t xb = (size_t)b * T_ * DIN;
        for (int t = 0; t < T_; t++) {
            float a, c2;
            ld2<BF16>(x, xb + (size_t)t*DIN + 2*tid, a, c2);
            s0 += a; s1 += c2;
        }
        xsL[2*tid] = s0; xsL[2*tid + 1] = s1;
    }
    __syncthreads();

    {
        const int k = tid & 63, seg = tid >> 6;
        float s = 0.0f;
        #pragma unroll 8
        for (int dd = 0; dd < 128; dd++) {
            int d = seg*128 + dd;
            s = fmaf(xsL[d], ld1<BF16>(Wth, (size_t)d*K_ + k), s);
        }
        red[tid] = s;
    }
    __syncthreads();

    if (tid < 64) {
        float s = red[tid] + red[64 + tid] + red[128 + tid] + red[192 + tid];
        float ang = 3.14159265358979323846f * (s + 2048.0f * ld1<BF16>(bth, tid));
        cosL[tid] = cosf(ang);
        sinL[tid] = sinf(ang);
    }
    __syncthreads();

    if (tid < 2) {
        const int j = tid;
        float s = ld1<BF16>(bpar, j);
        for (int k = 0; k < 64; k++) {
            s = fmaf(cosL[k], ld1<BF16>(Wpar, k*2 + j), s);
            s = fmaf(sinL[k], ld1<BF16>(Wpar, (64 + k)*2 + j), s);
        }
        if (BF16) ((u16*)out)[b*2 + j] = f2bf(s);
        else      ((float*)out)[b*2 + j] = s;
    }
}

extern "C" void kernel_launch(void* const* d_in, const int* in_sizes, int n_in,
                              void* d_out, int out_size, void* d_ws, size_t ws_size,
                              hipStream_t stream)
{
    const void* x     = d_in[0];
    const void* Wth   = d_in[1];
    const void* bth   = d_in[2];
    const void* Wlam  = d_in[3];
    const void* blam  = d_in[4];
    const void* Wdelt = d_in[5];
    const void* bdelt = d_in[6];
    const void* Winp  = d_in[7];
    const void* binp  = d_in[8];
    const void* Wpar  = d_in[9];
    const void* bpar  = d_in[10];
    const void* Wadd  = d_in[11];
    const void* badd  = d_in[12];

    const bool ws_col  = ws_size >= (size_t)WS_COL_FLOATS * 4;
    const bool ws_w    = ws_size >= (size_t)WS_W_OFF_F * 4 + (size_t)WS_W_PLANE_U32 * 2 * 4;
    const bool ws_full = ws_size >= (size_t)WS_FULL_BYTES;
    float* ws  = (float*)d_ws;
    u32*   wsw = (u32*)((char*)d_ws + WS_WFRAG_OFF_B);
    u32*   wsx = (u32*)((char*)d_ws + WS_XFRAG_OFF_B);

    zero_accum_kernel<<<1, 64, 0, stream>>>(x, d_out);

    // bf16 path: MFMA kernel (sniff-guarded; exits fast on fp32 inputs)
    fused_ssm_mfma_bf16<<<B_*16, 256, 0, stream>>>(
        x, Wlam, blam, Wdelt, bdelt, Winp, binp, Wadd, d_out);

    // fp32 path, tiered by workspace size
    if (ws_full) {
        convert_w_frag_kernel<<<256, 256, 0, stream>>>(x, Wlam, Wdelt, Winp, wsw);
        convert_x_kernel<<<8192, 256, 0, stream>>>(x, wsx);
        fused_ssm_mfma_fp32_full<<<B_*16, 256, 0, stream>>>(
            x, blam, bdelt, binp, Wadd, wsw, wsx, d_out);
    } else if (ws_w) {
        convert_w_kernel<<<768, 256, 0, stream>>>(x, Wlam, Wdelt, Winp, ws);
        fused_ssm_mfma_fp32_ws6<<<B_*16, 256, 0, stream>>>(
            x, blam, bdelt, binp, Wadd, ws, d_out);
    } else {
        fused_ssm_kernel<false><<<B_*MT, 256, 0, stream>>>(
            x, Wlam, blam, Wdelt, bdelt, Winp, binp, Wadd, d_out);
    }

    add_finalize_kernel<true ><<<1, 64, 0, stream>>>(x, badd, d_out);
    add_finalize_kernel<false><<<1, 64, 0, stream>>>(x, badd, d_out);

    if (ws_col) {
        colsum_zero_kernel<<<64, 256, 0, stream>>>(ws);
        parity_colsum_kernel<true ><<<256, 256, 0, stream>>>(x, ws);
        parity_colsum_kernel<false><<<256, 256, 0, stream>>>(x, ws);
        parity_finish_kernel<true ><<<B_, 256, 0, stream>>>(x, ws, Wth, bth, Wpar, bpar, d_out);
        parity_finish_kernel<false><<<B_, 256, 0, stream>>>(x, ws, Wth, bth, Wpar, bpar, d_out);
    } else {
        parity_kernel<true ><<<B_, 256, 0, stream>>>(x, Wth, bth, Wpar, bpar, d_out);
        parity_kernel<false><<<B_, 256, 0, stream>>>(x, Wth, bth, Wpar, bpar, d_out);
    }
}